// Round 9
// baseline (866.920 us; speedup 1.0000x reference)
//
#include <hip/hip_runtime.h>
#include <hip/hip_bf16.h>

typedef __hip_bfloat16 bf16;
typedef unsigned short u16;
typedef unsigned int u32;

typedef float f32x16 __attribute__((ext_vector_type(16)));
typedef short s16x8 __attribute__((ext_vector_type(8)));

__device__ __forceinline__ float b2f(bf16 v) { return __bfloat162float(v); }
__device__ __forceinline__ bf16  f2b(float v) { return __float2bfloat16(v); }
__device__ __forceinline__ float us2f(u16 u) { return __uint_as_float((u32)u << 16); }
__device__ __forceinline__ float ulo(u32 u)  { return __uint_as_float(u << 16); }
__device__ __forceinline__ float uhi(u32 u)  { return __uint_as_float(u & 0xFFFF0000u); }

// ---------------------------------------------------------------------------
// Static device arena (BSS, ~143 MB).  imgs NHWC3; crops NHWC3.
// ---------------------------------------------------------------------------
#define OFF_IMGS 0
#define OFF_C24  12441600
#define OFF_C48  15980544
#define OFF_WTS  19519488
#define OFF_A    20119488
#define OFF_B    54819488
#define OFF_RW   71319488
// repacked weights [o][tap][c] padded to NT*32 rows x KHW*CPAD cols
#define RW_RC2   (OFF_RW)            // 64 x  9x32 = 18432
#define RW_RC3   (OFF_RW + 18432)    // 64 x  4x48 = 12288
#define RW_OC2   (OFF_RW + 30720)    // 64 x  9x32 = 18432
#define RW_OC3   (OFF_RW + 49152)    // 64 x  9x64 = 36864
#define RW_OC4   (OFF_RW + 86016)    // 128 x 4x64 = 32768
#define RW_PC1   (OFF_RW + 118784)   // 32 x 9x16 = 4608
#define RW_PC2   (OFF_RW + 123392)   // 32 x 9x16 = 4608
#define RW_PC3   (OFF_RW + 128000)   // 32 x 9x16 = 4608
#define RW_RC1   (OFF_RW + 132608)   // 32 x 9x16 = 4608
#define RW_OC1   (OFF_RW + 137216)   // 32 x 9x16 = 4608
#define ARENA_N  (OFF_RW + 141824L)

__device__ bf16 g_arena[ARENA_N];
__device__ int  g_isf32;

// ---------------------------------------------------------------------------
// Dtype detection (bf16 N(0,1) never has exponent >= 0x8D; fp32 misread does).
// ---------------------------------------------------------------------------
__global__ void detect_kern(const void* imgs)
{
    if (threadIdx.x != 0) return;
    const u16* u = (const u16*)imgs;
    int f32 = 0;
    for (int i = 0; i < 256; ++i) {
        int e = (u[i] >> 7) & 0xFF;
        if (e >= 0x8D) f32 = 1;
    }
    g_isf32 = f32;
}

// imgs NCHW -> arena NHWC3  (out[((n*720+y)*720+x)*3+c])
__global__ void convert_img_kern(const void* __restrict__ src, int dst_off, int n)
{
    int i = blockIdx.x * blockDim.x + threadIdx.x;
    if (i >= n) return;
    int c = i % 3;
    int t = i / 3;
    int x = t % 720;
    int t2 = t / 720;
    int y = t2 % 720;
    int nn = t2 / 720;
    long si = ((long)(nn * 3 + c) * 720 + y) * 720 + x;
    float v = g_isf32 ? ((const float*)src)[si] : b2f(((const bf16*)src)[si]);
    g_arena[(long)dst_off + i] = f2b(v);
}

// crops NCHW -> arena NHWC3  (out[(n*HW+pix)*3+c])
__global__ void convert_crop_kern(const void* __restrict__ src, int dst_off, int HW, int n)
{
    int i = blockIdx.x * blockDim.x + threadIdx.x;
    if (i >= n) return;
    int c = i % 3;
    int t = i / 3;
    int pix = t % HW;
    int nn = t / HW;
    long si = ((long)(nn * 3 + c)) * HW + pix;
    float v = g_isf32 ? ((const float*)src)[si] : b2f(((const bf16*)src)[si]);
    g_arena[(long)dst_off + i] = f2b(v);
}

struct CvtEnt { const void* src; int dst_off; int n; };
struct CvtTab { CvtEnt e[50]; };
__global__ void convert_many_kern(CvtTab tab)
{
    CvtEnt ent = tab.e[blockIdx.y];
    int i = blockIdx.x * blockDim.x + threadIdx.x;
    if (i >= ent.n) return;
    float v = g_isf32 ? ((const float*)ent.src)[i] : b2f(((const bf16*)ent.src)[i]);
    g_arena[(long)ent.dst_off + i] = f2b(v);
}

__device__ __forceinline__ void stout(void* base, long idx, float v, int f32)
{
    if (f32) ((float*)base)[idx] = v;
    else     ((bf16*)base)[idx] = f2b(v);
}

// ---------------------------------------------------------------------------
// Weight repack for MFMA convs: w[o][c][tap] (torch OIHW) -> wr[o][tap][c],
// o padded to NT*32 rows, c padded to CPAD. B-fragment = 16B contiguous load.
// ---------------------------------------------------------------------------
__global__ void repack_w_kern(int w_off, int rw_off, int CO, int CIN, int CPAD,
                              int KHW, int total)
{
    int i = blockIdx.x * blockDim.x + threadIdx.x;
    if (i >= total) return;
    int c = i % CPAD;
    int t = i / CPAD;
    int g = t % KHW;
    int o = t / KHW;
    u16 v = 0;
    if (o < CO && c < CIN)
        v = ((const u16*)g_arena)[w_off + ((long)(o * CIN + c)) * KHW + g];
    ((u16*)g_arena)[(long)rw_off + i] = v;
}

// ---------------------------------------------------------------------------
// Crop-net conv1 (CIN=3) via MFMA 32x32x16 bf16, NHWC3 in -> NHWC out.
// half=1 lanes: K 8..15 all zero -> constant zero A frag; patchT PST=8.
// ---------------------------------------------------------------------------
template<int H,int W,int OH,int OW,int CO>
__launch_bounds__(256)
__global__ void conv1_mfma_kern(int in_off, int rw_off, int b_off, int a_off, int out_off)
{
    constexpr int PST = 8;
    constexpr int CO2 = CO + 2;
    __shared__ __align__(16) u16 patchT[10 * W * PST];
    __shared__ __align__(16) u16 out_s[8 * 32 * CO2];

    int n = blockIdx.x, by = blockIdx.y, tx = blockIdx.z;
    int gy0 = by * 8, gx0 = tx * 32;
    const u16* ga = (const u16*)g_arena;

    for (int i = threadIdx.x; i < 10 * W; i += 256)
        *(s16x8*)&patchT[i * PST] = (s16x8){};
    __syncthreads();
    for (int i = threadIdx.x; i < 10 * W * 3; i += 256) {
        int py = i / (W * 3), r = i - py * (W * 3);
        if (gy0 + py < H)
            patchT[(py * W + r / 3) * PST + r % 3] =
                ga[in_off + ((long)(n * H + gy0 + py) * W) * 3 + r];
    }
    __syncthreads();

    int lane = threadIdx.x & 63, w = threadIdx.x >> 6;
    int half = lane >> 5, m = lane & 31;
    int c0 = half * 8;

    s16x8 bfrag[9];
    {
        const u16* wbp = ga + rw_off + m * 144 + c0;
        #pragma unroll
        for (int g = 0; g < 9; ++g)
            bfrag[g] = *(const s16x8*)(wbp + g * 16);
    }
    float bb = (m < CO) ? us2f(ga[b_off + m]) : 0.f;
    float aa = (m < CO) ? us2f(ga[a_off + m]) : 0.f;

    s16x8 azero = {};
    f32x16 acc0 = {}, acc1 = {};
    #pragma unroll
    for (int g = 0; g < 9; ++g) {
        int ky = g / 3, kx = g % 3;
        int cx = gx0 + m + kx; if (cx > W - 1) cx = W - 1;
        s16x8 a0 = half ? azero : *(const s16x8*)&patchT[((2 * w + 0 + ky) * W + cx) * PST];
        s16x8 a1 = half ? azero : *(const s16x8*)&patchT[((2 * w + 1 + ky) * W + cx) * PST];
        acc0 = __builtin_amdgcn_mfma_f32_32x32x16_bf16(a0, bfrag[g], acc0, 0, 0, 0);
        acc1 = __builtin_amdgcn_mfma_f32_32x32x16_bf16(a1, bfrag[g], acc1, 0, 0, 0);
    }

    if (m < CO) {
        #pragma unroll
        for (int s = 0; s < 2; ++s) {
            const f32x16& A = s ? acc1 : acc0;
            int r = 2 * w + s;
            #pragma unroll
            for (int reg = 0; reg < 16; ++reg) {
                int x = (reg & 3) + 8 * (reg >> 2) + 4 * half;
                float v = A[reg] + bb;
                v = v > 0.f ? v : v * aa;
                u16 bits; bf16 t = f2b(v); __builtin_memcpy(&bits, &t, 2);
                out_s[(r * 32 + x) * CO2 + m] = bits;
            }
        }
    }
    __syncthreads();

    int nrowv = OH - gy0; if (nrowv > 8) nrowv = 8;
    int ncolv = OW - gx0; if (ncolv > 32) ncolv = 32;
    int cw = ncolv * (CO / 2);
    int totw = nrowv * cw;
    const u32* osrc = (const u32*)out_s;
    for (int i = threadIdx.x; i < totw; i += 256) {
        int r = i / cw, rem = i - r * cw;
        int x = rem / (CO / 2), op = rem - x * (CO / 2);
        u32 v = osrc[(r * 32 + x) * (CO2 / 2) + op];
        *(u32*)&g_arena[(long)out_off +
            (((long)(n * OH + gy0 + r)) * OW + gx0 + x) * CO + 2 * op] = v;
    }
}

// ---------------------------------------------------------------------------
// MFMA conv for channel-rich crop-net layers (CIN >= 16).
// ---------------------------------------------------------------------------
template<int CIN,int CPAD,int KH,int KW,int H,int W,int OH,int OW,int CO,int NT>
__launch_bounds__(256, 2)
__global__ void conv_mfma_kern(int in_off, int rw_off, int b_off, int a_off, int out_off)
{
    constexpr int NPX = OH * OW;
    constexpr int MT = (NPX + 31) / 32;
    constexpr int PST = CPAD + 8;
    constexpr int NCH = CPAD / 16;
    constexpr int KHW = KH * KW;
    constexpr int NG = KHW * NCH;
    __shared__ __align__(16) u16 patchT[H * W * PST];

    int n = blockIdx.x;
    const u16* ga = (const u16*)g_arena;
    const u16* in = ga + in_off + (long)n * (H * W * CIN);

    if constexpr (CIN == CPAD) {
        constexpr int NV = H * W * (CPAD / 8);
        for (int i = threadIdx.x; i < NV; i += 256) {
            int pix = i / (CPAD / 8), j = i % (CPAD / 8);
            *(s16x8*)&patchT[pix * PST + j * 8] = *(const s16x8*)&in[pix * CPAD + j * 8];
        }
    } else {
        constexpr int TOT = H * W * CPAD;
        for (int i = threadIdx.x; i < TOT; i += 256) {
            int pix = i / CPAD, c = i % CPAD;
            patchT[pix * PST + c] = (c < CIN) ? in[pix * CIN + c] : (u16)0;
        }
    }
    __syncthreads();

    int m = threadIdx.x & 31, half = (threadIdx.x >> 5) & 1, wave = threadIdx.x >> 6;
    int c0 = half * 8;
    int nt = wave % NT;
    int o = nt * 32 + m;
    bool ovld = o < CO;
    float bb = ovld ? us2f(ga[b_off + o]) : 0.f;
    float aa = ovld ? us2f(ga[a_off + o]) : 0.f;

    s16x8 bfrag[NG];
    const u16* wb = ga + rw_off + (long)(nt * 32 + m) * (KHW * CPAD) + c0;
    #pragma unroll
    for (int g = 0; g < NG; ++g)
        bfrag[g] = *(const s16x8*)(wb + g * 16);

    for (int mt = wave / NT; mt < MT; mt += 4 / NT) {
        int p = mt * 32 + m;
        int pc = p < NPX ? p : NPX - 1;
        int pp = (pc / OW) * W + (pc % OW);
        f32x16 acc = {};
        #pragma unroll
        for (int t = 0; t < KHW; ++t) {
            int rb = (pp + (t / KW) * W + (t % KW)) * PST + c0;
            #pragma unroll
            for (int ch = 0; ch < NCH; ++ch) {
                s16x8 a = *(const s16x8*)&patchT[rb + ch * 16];
                acc = __builtin_amdgcn_mfma_f32_32x32x16_bf16(a, bfrag[t * NCH + ch], acc, 0, 0, 0);
            }
        }
        if (ovld) {
            bf16* op = g_arena + (long)out_off + (long)n * (NPX * CO) + o;
            #pragma unroll
            for (int reg = 0; reg < 16; ++reg) {
                int mrow = (reg & 3) + 8 * (reg >> 2) + 4 * half;
                int pr = mt * 32 + mrow;
                if (pr < NPX) {
                    float v = acc[reg] + bb;
                    v = v > 0.f ? v : v * aa;
                    op[(long)pr * CO] = f2b(v);
                }
            }
        }
    }
}

// ---------------------------------------------------------------------------
// PNet conv1 (3->10) + PReLU + fused maxpool 2x2 s2 via MFMA 32x32x16 bf16.
// v4: PST=8 + half-zero-A (from conv1_mfma): patchT 29.4->9.8 KB (occupancy
// 3->8 blocks/CU), half=0 A-reads = 32 lanes x contiguous 16B = conflict-free.
// ---------------------------------------------------------------------------
__launch_bounds__(256)
__global__ void pnet_c1m_kern(int b_off, int a_off, int out_off)
{
    constexpr int PST = 8;
    __shared__ __align__(16) u16 patchT[612 * PST];   // 9792 B
    __shared__ __align__(16) u16 out_s[8 * 16 * 10];  // 2560 B
    __shared__ float b1s[16], a1s[16];

    int n = blockIdx.x, by = blockIdx.y, tx = blockIdx.z;
    int gy0 = by * 16, gx0 = tx * 32;
    const u16* ga = (const u16*)g_arena;

    // vector-zero patchT (one 16B slot per pixel)
    for (int i = threadIdx.x; i < 612; i += 256)
        *(s16x8*)&patchT[i * PST] = (s16x8){};
    if (threadIdx.x < 16) {
        b1s[threadIdx.x] = (threadIdx.x < 10) ? us2f(ga[b_off + threadIdx.x]) : 0.f;
        a1s[threadIdx.x] = (threadIdx.x < 10) ? us2f(ga[a_off + threadIdx.x]) : 0.f;
    }
    __syncthreads();

    // stage the 18x34x3 valid region: coalesced contiguous u16 loads
    for (int i = threadIdx.x; i < 18 * 128; i += 256) {
        int py = i >> 7, r = i & 127;
        if (r < 102) {
            int pxx = r / 3, c = r - pxx * 3;
            int iy = gy0 + py, ix = gx0 + pxx;
            if (iy < 720 && ix < 720)
                patchT[(py * 34 + pxx) * PST + c] =
                    ga[OFF_IMGS + (((long)n * 720 + iy) * 720 + ix) * 3 + c];
        }
    }
    __syncthreads();

    int lane = threadIdx.x & 63, w = threadIdx.x >> 6;
    int half = lane >> 5, m = lane & 31;
    int c0 = half * 8;

    s16x8 bfrag[9];
    {
        const u16* wbp = ga + RW_PC1 + m * 144 + c0;
        #pragma unroll
        for (int g = 0; g < 9; ++g)
            bfrag[g] = *(const s16x8*)(wbp + g * 16);
    }

    s16x8 azero = {};
    f32x16 acc[4] = {};
    #pragma unroll
    for (int g = 0; g < 9; ++g) {
        int ky = g / 3, kx = g % 3;
        #pragma unroll
        for (int rj = 0; rj < 4; ++rj) {
            s16x8 a = half ? azero
                : *(const s16x8*)&patchT[((4 * w + rj + ky) * 34 + m + kx) * PST];
            acc[rj] = __builtin_amdgcn_mfma_f32_32x32x16_bf16(a, bfrag[g], acc[rj], 0, 0, 0);
        }
    }

    // bias + PReLU + 2x2 max (thread-local) -> out_s[lr][pxo][m]
    if (m < 10) {
        float b = b1s[m], al = a1s[m];
        #pragma unroll
        for (int s = 0; s < 2; ++s) {
            int lr = 2 * w + s;
            #pragma unroll
            for (int u = 0; u < 8; ++u) {
                int pxo = (u & 1) + 4 * (u >> 1) + 2 * half;
                float v0 = acc[2 * s][2 * u] + b;         v0 = v0 > 0.f ? v0 : v0 * al;
                float v1 = acc[2 * s][2 * u + 1] + b;     v1 = v1 > 0.f ? v1 : v1 * al;
                float v2 = acc[2 * s + 1][2 * u] + b;     v2 = v2 > 0.f ? v2 : v2 * al;
                float v3 = acc[2 * s + 1][2 * u + 1] + b; v3 = v3 > 0.f ? v3 : v3 * al;
                float mx = fmaxf(fmaxf(v0, v1), fmaxf(v2, v3));
                u16 bits; bf16 t = f2b(mx); __builtin_memcpy(&bits, &t, 2);
                out_s[(lr * 16 + pxo) * 10 + m] = bits;
            }
        }
    }
    __syncthreads();

    int nrowv = 359 - by * 8; if (nrowv > 8) nrowv = 8;
    int ncolv = 359 - tx * 16; if (ncolv > 16) ncolv = 16;
    int cw = ncolv * 5;
    int totw = nrowv * cw;
    for (int i = threadIdx.x; i < totw; i += 256) {
        int j = i / cw, rem = i - j * cw;
        u32 v = ((const u32*)out_s)[j * 80 + rem];
        *(u32*)&g_arena[(long)out_off +
            (((long)n * 359 + by * 8 + j) * 359 + tx * 16) * 10 + rem * 2] = v;
    }
}

// ---------------------------------------------------------------------------
// PNet conv2 (10->16) via MFMA 32x32x16 bf16.  NHWC in (10ch), NHWC out (16ch).
// ---------------------------------------------------------------------------
__launch_bounds__(256)
__global__ void pnet_c2m_kern(int in_off, int b_off, int a_off, int out_off)
{
    constexpr int PST = 24;
    __shared__ __align__(16) u16 patchT[340 * PST];   // 16320 B
    __shared__ float b2s[16], a2s[16];

    int n = blockIdx.x, by = blockIdx.y, tx = blockIdx.z;
    int gy0 = by * 8, gx0 = tx * 32;
    const u16* ga = (const u16*)g_arena;

    for (int i = threadIdx.x; i < 5440; i += 256) {
        int pix = i >> 4, c = i & 15;
        int py = pix / 34, pxx = pix % 34;
        int iy = gy0 + py, ix = gx0 + pxx;
        u16 v = 0;
        if (c < 10 && iy < 359 && ix < 359)
            v = ga[in_off + ((long)(n * 359 + iy) * 359 + ix) * 10 + c];
        patchT[pix * PST + c] = v;
    }
    if (threadIdx.x < 16) {
        b2s[threadIdx.x] = us2f(ga[b_off + threadIdx.x]);
        a2s[threadIdx.x] = us2f(ga[a_off + threadIdx.x]);
    }
    __syncthreads();

    int lane = threadIdx.x & 63, w = threadIdx.x >> 6;
    int half = lane >> 5, m = lane & 31;
    int c0 = half * 8;

    s16x8 bfrag[9];
    {
        const u16* wbp = ga + RW_PC2 + m * 144 + c0;
        #pragma unroll
        for (int g = 0; g < 9; ++g)
            bfrag[g] = *(const s16x8*)(wbp + g * 16);
    }

    f32x16 acc0 = {}, acc1 = {};
    #pragma unroll
    for (int g = 0; g < 9; ++g) {
        int ky = g / 3, kx = g % 3;
        s16x8 a0 = *(const s16x8*)&patchT[((2 * w + 0 + ky) * 34 + m + kx) * PST + c0];
        s16x8 a1 = *(const s16x8*)&patchT[((2 * w + 1 + ky) * 34 + m + kx) * PST + c0];
        acc0 = __builtin_amdgcn_mfma_f32_32x32x16_bf16(a0, bfrag[g], acc0, 0, 0, 0);
        acc1 = __builtin_amdgcn_mfma_f32_32x32x16_bf16(a1, bfrag[g], acc1, 0, 0, 0);
    }

    if (m < 16) {
        float b = b2s[m], al = a2s[m];
        #pragma unroll
        for (int reg = 0; reg < 16; ++reg) {
            int mrow = (reg & 3) + 8 * (reg >> 2) + 4 * half;
            int gy = gy0 + 2 * w, gx = gx0 + mrow;
            if (gy < 357 && gx < 357) {
                float v = acc0[reg] + b; v = v > 0.f ? v : v * al;
                g_arena[(long)out_off + (((long)(n * 357 + gy)) * 357 + gx) * 16 + m] = f2b(v);
            }
            if (gy + 1 < 357 && gx < 357) {
                float v = acc1[reg] + b; v = v > 0.f ? v : v * al;
                g_arena[(long)out_off + (((long)(n * 357 + gy + 1)) * 357 + gx) * 16 + m] = f2b(v);
            }
        }
    }
}

// ---------------------------------------------------------------------------
// PNet conv3 (16->32) + PReLU + heads, conv via MFMA 32x32x16 bf16.
// ---------------------------------------------------------------------------
__launch_bounds__(256)
__global__ void pnet_c3h_kern(int in_off, int b3o, int a3o,
                              int w41o, int b41o, int w42o, int b42o, void* dout)
{
    constexpr int PST = 24;
    __shared__ __align__(16) u16 patchT[340 * PST];   // 16320 B
    __shared__ float c3s[256 * 33];                   // 33792 B
    __shared__ float b3f[32], a3f[32], w41f[64], w42f[128], b41f[2], b42f[4];

    int n = blockIdx.x, by = blockIdx.y, tx = blockIdx.z;
    int gy0 = by * 8, gx0 = tx * 32;
    const u16* ga = (const u16*)g_arena;

    for (int i = threadIdx.x; i < 680; i += 256) {
        int pix = i >> 1, h = i & 1;
        int py = pix / 34, pxx = pix % 34;
        int iy = gy0 + py, ix = gx0 + pxx;
        s16x8 v = {};
        if (iy < 357 && ix < 357)
            v = *(const s16x8*)&ga[in_off + (((long)(n * 357 + iy)) * 357 + ix) * 16 + h * 8];
        *(s16x8*)&patchT[pix * PST + h * 8] = v;
    }
    for (int i = threadIdx.x; i < 32; i += 256) { b3f[i] = us2f(ga[b3o + i]); a3f[i] = us2f(ga[a3o + i]); }
    for (int i = threadIdx.x; i < 64; i += 256) w41f[i] = us2f(ga[w41o + i]);
    for (int i = threadIdx.x; i < 128; i += 256) w42f[i] = us2f(ga[w42o + i]);
    if (threadIdx.x < 2) b41f[threadIdx.x] = us2f(ga[b41o + threadIdx.x]);
    if (threadIdx.x < 4) b42f[threadIdx.x] = us2f(ga[b42o + threadIdx.x]);
    __syncthreads();

    int lane = threadIdx.x & 63, w = threadIdx.x >> 6;
    int half = lane >> 5, m = lane & 31;
    int c0 = half * 8;

    s16x8 bfrag[9];
    {
        const u16* wbp = ga + RW_PC3 + m * 144 + c0;
        #pragma unroll
        for (int g = 0; g < 9; ++g)
            bfrag[g] = *(const s16x8*)(wbp + g * 16);
    }

    f32x16 acc0 = {}, acc1 = {};
    #pragma unroll
    for (int g = 0; g < 9; ++g) {
        int ky = g / 3, kx = g % 3;
        s16x8 a0 = *(const s16x8*)&patchT[((2 * w + 0 + ky) * 34 + m + kx) * PST + c0];
        s16x8 a1 = *(const s16x8*)&patchT[((2 * w + 1 + ky) * 34 + m + kx) * PST + c0];
        acc0 = __builtin_amdgcn_mfma_f32_32x32x16_bf16(a0, bfrag[g], acc0, 0, 0, 0);
        acc1 = __builtin_amdgcn_mfma_f32_32x32x16_bf16(a1, bfrag[g], acc1, 0, 0, 0);
    }

    {
        float b = b3f[m], al = a3f[m];
        #pragma unroll
        for (int reg = 0; reg < 16; ++reg) {
            int mrow = (reg & 3) + 8 * (reg >> 2) + 4 * half;
            float v0 = acc0[reg] + b; v0 = v0 > 0.f ? v0 : v0 * al;
            c3s[(w * 64 + mrow) * 33 + m] = v0;
            float v1 = acc1[reg] + b; v1 = v1 > 0.f ? v1 : v1 * al;
            c3s[(w * 64 + 32 + mrow) * 33 + m] = v1;
        }
    }
    __syncthreads();

    int p = threadIdx.x;
    int gy = gy0 + (p >> 5), gx = gx0 + (p & 31);
    if (gy < 355 && gx < 355) {
        int f32 = g_isf32;
        float l0 = b41f[0], l1 = b41f[1];
        float r0 = b42f[0], r1 = b42f[1], r2 = b42f[2], r3 = b42f[3];
        #pragma unroll
        for (int o = 0; o < 32; ++o) {
            float v = c3s[p * 33 + o];
            l0 += v * w41f[o];
            l1 += v * w41f[32 + o];
            r0 += v * w42f[o];
            r1 += v * w42f[32 + o];
            r2 += v * w42f[64 + o];
            r3 += v * w42f[96 + o];
        }
        float mx = fmaxf(l0, l1);
        float e0 = __expf(l0 - mx), e1 = __expf(l1 - mx);
        float inv = 1.f / (e0 + e1);
        const long HW = 355L * 355L;
        long pix = (long)gy * 355 + gx;
        stout(dout, 4032800 + ((long)n * 2 + 0) * HW + pix, e0 * inv, f32);
        stout(dout, 4032800 + ((long)n * 2 + 1) * HW + pix, e1 * inv, f32);
        stout(dout, ((long)n * 4 + 0) * HW + pix, r0, f32);
        stout(dout, ((long)n * 4 + 1) * HW + pix, r1, f32);
        stout(dout, ((long)n * 4 + 2) * HW + pix, r2, f32);
        stout(dout, ((long)n * 4 + 3) * HW + pix, r3, f32);
    }
}

// ---------------------------------------------------------------------------
// MaxPool2d ceil_mode, NHWC -> NHWC (fully coalesced both sides).
// ---------------------------------------------------------------------------
__global__ void maxpool_nhwc_kern(int in_off, int out_off, int C, int H, int W,
                                  int OH, int OW, int k, int s, int total)
{
    int tid = blockIdx.x * blockDim.x + threadIdx.x;
    if (tid >= total) return;
    int c = tid % C; int t = tid / C;
    int ox = t % OW; t /= OW;
    int oy = t % OH; int n = t / OH;
    const u16* ip = (const u16*)g_arena + in_off + (long)n * H * W * C + c;
    int sy = oy * s, sx = ox * s;
    float m = -1e30f;
    for (int ky = 0; ky < k; ++ky) {
        int iy = sy + ky;
        if (iy >= H) break;
        for (int kx = 0; kx < k; ++kx) {
            int ix = sx + kx;
            if (ix >= W) break;
            m = fmaxf(m, us2f(ip[(iy * W + ix) * C]));
        }
    }
    g_arena[(long)out_off + tid] = f2b(m);
}

// ---------------------------------------------------------------------------
// Flatten from NHWC: torch permute(0,3,2,1).view == h<->w swap on NHWC.
// ---------------------------------------------------------------------------
__global__ void flatten_hw_kern(int in_off, int out_off, int C, int H, int W, int total)
{
    int tid = blockIdx.x * blockDim.x + threadIdx.x;
    if (tid >= total) return;
    int CHW = C * H * W;
    int n = tid / CHW;
    int k = tid % CHW;
    int w = k / (H * C);
    int r = k % (H * C);
    int h = r / C;
    int c = r % C;
    g_arena[(long)out_off + tid] =
        g_arena[(long)in_off + ((long)n * H * W + h * W + w) * C + c];
}

// ---------------------------------------------------------------------------
// Dense + bias + PReLU as tiled LDS GEMM (32x32 tile, 2x2 micro-tile).
// ---------------------------------------------------------------------------
__launch_bounds__(256)
__global__ void dense_tile_kern(int in_off, int w_off, int b_off, int a_off, int out_off,
                                int K, int J)
{
    __shared__ u16 in_s[32 * 66];
    __shared__ u16 w_s[32 * 66];
    int n0 = blockIdx.x * 32, j0 = blockIdx.y * 32;
    const u16* ga = (const u16*)g_arena;
    const u16* fin = ga + in_off;
    const u16* wts = ga + w_off;
    int sy = threadIdx.x >> 4, sx = threadIdx.x & 15;

    float acc00 = 0.f, acc01 = 0.f, acc10 = 0.f, acc11 = 0.f;

    for (int kc = 0; kc < K; kc += 64) {
        #pragma unroll
        for (int it = 0; it < 4; ++it) {
            int i = threadIdx.x + it * 256;
            int row = i >> 5, c2 = i & 31;
            u32 v = *(const u32*)(fin + (long)(n0 + row) * K + kc + c2 * 2);
            *(u32*)&in_s[row * 66 + c2 * 2] = v;
            u32 wv = *(const u32*)(wts + (long)(j0 + row) * K + kc + c2 * 2);
            *(u32*)&w_s[row * 66 + c2 * 2] = wv;
        }
        __syncthreads();
        #pragma unroll
        for (int kk = 0; kk < 64; ++kk) {
            float a0 = us2f(in_s[(2 * sy) * 66 + kk]);
            float a1 = us2f(in_s[(2 * sy + 1) * 66 + kk]);
            float b0 = us2f(w_s[(2 * sx) * 66 + kk]);
            float b1 = us2f(w_s[(2 * sx + 1) * 66 + kk]);
            acc00 += a0 * b0; acc01 += a0 * b1;
            acc10 += a1 * b0; acc11 += a1 * b1;
        }
        __syncthreads();
    }

    float accs[2][2] = {{acc00, acc01}, {acc10, acc11}};
    #pragma unroll
    for (int jj = 0; jj < 2; ++jj) {
        int j = j0 + 2 * sx + jj;
        float b = us2f(ga[b_off + j]);
        float al = us2f(ga[a_off + j]);
        #pragma unroll
        for (int ss = 0; ss < 2; ++ss) {
            int n = n0 + 2 * sy + ss;
            float v = accs[ss][jj] + b;
            v = v > 0.f ? v : v * al;
            g_arena[(long)out_off + (long)n * J + j] = f2b(v);
        }
    }
}

// ---------------------------------------------------------------------------
// Heads, wave-per-sample: 64 lanes partition K; butterfly shuffle reduction.
// ---------------------------------------------------------------------------
template<int K, int J1, int J2>
__launch_bounds__(256)
__global__ void heads_wave_kern(int fc_off, int wSo, int bSo, int w1o, int b1o,
                                int w2o, int b2o, void* dout,
                                long outS_off, long out1_off, long out2_off, int N)
{
    constexpr int KPL = K / 64;
    constexpr int NACC = 2 + J1 + J2;
    int wave = (blockIdx.x * blockDim.x + threadIdx.x) >> 6;
    int lane = threadIdx.x & 63;
    if (wave >= N) return;
    const u16* ga = (const u16*)g_arena;
    const u16* f  = ga + fc_off + (long)wave * K;
    const u16* wS = ga + wSo;
    const u16* w1 = ga + w1o;
    const u16* w2 = ga + w2o;

    float acc[NACC];
    #pragma unroll
    for (int j = 0; j < NACC; ++j) acc[j] = 0.f;

    #pragma unroll
    for (int kk = 0; kk < KPL; ++kk) {
        int k = lane + kk * 64;
        float fv = us2f(f[k]);
        acc[0] += fv * us2f(wS[k]);
        acc[1] += fv * us2f(wS[K + k]);
        #pragma unroll
        for (int j = 0; j < J1; ++j)
            acc[2 + j] += fv * us2f(w1[j * K + k]);
        #pragma unroll
        for (int j = 0; j < J2; ++j)
            acc[2 + J1 + j] += fv * us2f(w2[j * K + k]);
    }
    #pragma unroll
    for (int j = 0; j < NACC; ++j)
        #pragma unroll
        for (int off = 32; off > 0; off >>= 1)
            acc[j] += __shfl_xor(acc[j], off, 64);

    if (lane == 0) {
        int f32 = g_isf32;
        float l0 = acc[0] + us2f(ga[bSo + 0]);
        float l1 = acc[1] + us2f(ga[bSo + 1]);
        float m = fmaxf(l0, l1);
        float e0 = __expf(l0 - m), e1 = __expf(l1 - m);
        float inv = 1.f / (e0 + e1);
        stout(dout, outS_off + (long)wave * 2 + 0, e0 * inv, f32);
        stout(dout, outS_off + (long)wave * 2 + 1, e1 * inv, f32);
        #pragma unroll
        for (int j = 0; j < J1; ++j)
            stout(dout, out1_off + (long)wave * J1 + j, acc[2 + j] + us2f(ga[b1o + j]), f32);
        #pragma unroll
        for (int j = 0; j < J2; ++j)
            stout(dout, out2_off + (long)wave * J2 + j, acc[2 + J1 + j] + us2f(ga[b2o + j]), f32);
    }
}

static inline dim3 g1(int total) { return dim3((unsigned)((total + 255) / 256)); }

extern "C" void kernel_launch(void* const* d_in, const int* in_sizes, int n_in,
                              void* d_out, int out_size, void* d_ws, size_t ws_size,
                              hipStream_t stream)
{
    int woff[53];
    int acc = OFF_WTS;
    int mx = 0;
    for (int i = 3; i < 53; ++i) { woff[i] = acc; acc += in_sizes[i]; if (in_sizes[i] > mx) mx = in_sizes[i]; }

    detect_kern<<<1, 64, 0, stream>>>(d_in[0]);
    convert_img_kern<<<g1(12441600), 256, 0, stream>>>(d_in[0], OFF_IMGS, 12441600);
    convert_crop_kern<<<g1(3538944), 256, 0, stream>>>(d_in[1], OFF_C24, 576, 3538944);
    convert_crop_kern<<<g1(3538944), 256, 0, stream>>>(d_in[2], OFF_C48, 2304, 3538944);
    CvtTab tab;
    for (int i = 3; i < 53; ++i) tab.e[i - 3] = CvtEnt{ d_in[i], woff[i], in_sizes[i] };
    convert_many_kern<<<dim3((unsigned)((mx + 255) / 256), 50), 256, 0, stream>>>(tab);

    // repack weights for the MFMA convs (after convert_many)
    repack_w_kern<<<g1(4608), 256, 0, stream>>>(woff[3], RW_PC1, 10, 3, 16, 9, 4608);
    repack_w_kern<<<g1(4608), 256, 0, stream>>>(woff[6], RW_PC2, 16, 10, 16, 9, 4608);
    repack_w_kern<<<g1(4608), 256, 0, stream>>>(woff[9], RW_PC3, 32, 16, 16, 9, 4608);
    repack_w_kern<<<g1(4608), 256, 0, stream>>>(woff[16], RW_RC1, 28, 3, 16, 9, 4608);
    repack_w_kern<<<g1(18432), 256, 0, stream>>>(woff[19], RW_RC2, 48, 28, 32, 9, 18432);
    repack_w_kern<<<g1(12288), 256, 0, stream>>>(woff[22], RW_RC3, 64, 48, 48, 4, 12288);
    repack_w_kern<<<g1(4608), 256, 0, stream>>>(woff[32], RW_OC1, 32, 3, 16, 9, 4608);
    repack_w_kern<<<g1(18432), 256, 0, stream>>>(woff[35], RW_OC2, 64, 32, 32, 9, 18432);
    repack_w_kern<<<g1(36864), 256, 0, stream>>>(woff[38], RW_OC3, 64, 64, 64, 9, 36864);
    repack_w_kern<<<g1(32768), 256, 0, stream>>>(woff[41], RW_OC4, 128, 64, 64, 4, 32768);

    // ================= PNet (NHWC end-to-end) =================
    pnet_c1m_kern<<<dim3(8, 45, 23), 256, 0, stream>>>(woff[4], woff[5], OFF_A);
    pnet_c2m_kern<<<dim3(8, 45, 12), 256, 0, stream>>>(OFF_A, woff[7], woff[8], OFF_B);
    pnet_c3h_kern<<<dim3(8, 45, 12), 256, 0, stream>>>(OFF_B,
        woff[10], woff[11], woff[12], woff[13], woff[14], woff[15], d_out);

    // ================= RNet (NHWC end-to-end) =================
    conv1_mfma_kern<24,24,22,22,28><<<dim3(2048, 3, 1), 256, 0, stream>>>(
        OFF_C24, RW_RC1, woff[17], woff[18], OFF_A);
    maxpool_nhwc_kern<<<g1(6938624), 256, 0, stream>>>(OFF_A, OFF_B, 28, 22, 22, 11, 11, 3, 2, 6938624);
    conv_mfma_kern<28,32,3,3,11,11,9,9,48,2><<<dim3(2048), 256, 0, stream>>>(
        OFF_B, RW_RC2, woff[20], woff[21], OFF_A);
    maxpool_nhwc_kern<<<g1(1572864), 256, 0, stream>>>(OFF_A, OFF_B, 48, 9, 9, 4, 4, 3, 2, 1572864);
    conv_mfma_kern<48,48,2,2,4,4,3,3,64,2><<<dim3(2048), 256, 0, stream>>>(
        OFF_B, RW_RC3, woff[23], woff[24], OFF_A);
    flatten_hw_kern<<<g1(1179648), 256, 0, stream>>>(OFF_A, OFF_B, 64, 3, 3, 1179648);
    dense_tile_kern<<<dim3(64, 4), 256, 0, stream>>>(OFF_B, woff[25], woff[26], woff[27], OFF_A,
        576, 128);
    heads_wave_kern<128,4,0><<<dim3(512), 256, 0, stream>>>(OFF_A,
        woff[28], woff[29], woff[30], woff[31], 0, 0,
        d_out, 6057392L, 6049200L, 0L, 2048);

    // ================= ONet (NHWC end-to-end) =================
    conv1_mfma_kern<48,48,46,46,32><<<dim3(512, 6, 2), 256, 0, stream>>>(
        OFF_C48, RW_OC1, woff[33], woff[34], OFF_A);
    maxpool_nhwc_kern<<<g1(8667136), 256, 0, stream>>>(OFF_A, OFF_B, 32, 46, 46, 23, 23, 3, 2, 8667136);
    conv_mfma_kern<32,32,3,3,23,23,21,21,64,2><<<dim3(512), 256, 0, stream>>>(
        OFF_B, RW_OC2, woff[36], woff[37], OFF_A);
    maxpool_nhwc_kern<<<g1(3276800), 256, 0, stream>>>(OFF_A, OFF_B, 64, 21, 21, 10, 10, 3, 2, 3276800);
    conv_mfma_kern<64,64,3,3,10,10,8,8,64,2><<<dim3(512), 256, 0, stream>>>(
        OFF_B, RW_OC3, woff[39], woff[40], OFF_A);
    maxpool_nhwc_kern<<<g1(524288), 256, 0, stream>>>(OFF_A, OFF_B, 64, 8, 8, 4, 4, 2, 2, 524288);
    conv_mfma_kern<64,64,2,2,4,4,3,3,128,4><<<dim3(512), 256, 0, stream>>>(
        OFF_B, RW_OC4, woff[42], woff[43], OFF_A);
    flatten_hw_kern<<<g1(589824), 256, 0, stream>>>(OFF_A, OFF_B, 128, 3, 3, 589824);
    dense_tile_kern<<<dim3(16, 8), 256, 0, stream>>>(OFF_B, woff[44], woff[45], woff[46], OFF_A,
        1152, 256);
    heads_wave_kern<256,4,10><<<dim3(128), 256, 0, stream>>>(OFF_A,
        woff[47], woff[48], woff[49], woff[50], woff[51], woff[52],
        d_out, 6068656L, 6061488L, 6063536L, 512);
}

// Round 10
// 837.474 us; speedup vs baseline: 1.0352x; 1.0352x over previous
//
#include <hip/hip_runtime.h>
#include <hip/hip_bf16.h>

typedef __hip_bfloat16 bf16;
typedef unsigned short u16;
typedef unsigned int u32;

typedef float f32x16 __attribute__((ext_vector_type(16)));
typedef short s16x8 __attribute__((ext_vector_type(8)));

__device__ __forceinline__ float b2f(bf16 v) { return __bfloat162float(v); }
__device__ __forceinline__ bf16  f2b(float v) { return __float2bfloat16(v); }
__device__ __forceinline__ float us2f(u16 u) { return __uint_as_float((u32)u << 16); }
__device__ __forceinline__ float ulo(u32 u)  { return __uint_as_float(u << 16); }
__device__ __forceinline__ float uhi(u32 u)  { return __uint_as_float(u & 0xFFFF0000u); }

// ---------------------------------------------------------------------------
// Static device arena (BSS, ~143 MB).  imgs NHWC3; crops NHWC3.
// ---------------------------------------------------------------------------
#define OFF_IMGS 0
#define OFF_C24  12441600
#define OFF_C48  15980544
#define OFF_WTS  19519488
#define OFF_A    20119488
#define OFF_B    54819488
#define OFF_RW   71319488
// repacked weights
#define RW_RC2   (OFF_RW)            // 64 x  9x32 = 18432
#define RW_RC3   (OFF_RW + 18432)    // 64 x  4x48 = 12288
#define RW_OC2   (OFF_RW + 30720)    // 64 x  9x32 = 18432
#define RW_OC3   (OFF_RW + 49152)    // 64 x  9x64 = 36864
#define RW_OC4   (OFF_RW + 86016)    // 128 x 4x64 = 32768
#define RW_PC1   (OFF_RW + 118784)   // 32 x 5x16 = 2560 (tap-pair packed)
#define RW_PC2   (OFF_RW + 123392)   // 32 x 9x16 = 4608
#define RW_PC3   (OFF_RW + 128000)   // 32 x 9x16 = 4608
#define RW_RC1   (OFF_RW + 132608)   // 32 x 5x16 = 2560 (tap-pair packed)
#define RW_OC1   (OFF_RW + 137216)   // 32 x 5x16 = 2560 (tap-pair packed)
#define ARENA_N  (OFF_RW + 141824L)

__device__ bf16 g_arena[ARENA_N];
__device__ int  g_isf32;

// ---------------------------------------------------------------------------
// Dtype detection (bf16 N(0,1) never has exponent >= 0x8D; fp32 misread does).
// ---------------------------------------------------------------------------
__global__ void detect_kern(const void* imgs)
{
    if (threadIdx.x != 0) return;
    const u16* u = (const u16*)imgs;
    int f32 = 0;
    for (int i = 0; i < 256; ++i) {
        int e = (u[i] >> 7) & 0xFF;
        if (e >= 0x8D) f32 = 1;
    }
    g_isf32 = f32;
}

// imgs NCHW -> arena NHWC3  (out[((n*720+y)*720+x)*3+c])
__global__ void convert_img_kern(const void* __restrict__ src, int dst_off, int n)
{
    int i = blockIdx.x * blockDim.x + threadIdx.x;
    if (i >= n) return;
    int c = i % 3;
    int t = i / 3;
    int x = t % 720;
    int t2 = t / 720;
    int y = t2 % 720;
    int nn = t2 / 720;
    long si = ((long)(nn * 3 + c) * 720 + y) * 720 + x;
    float v = g_isf32 ? ((const float*)src)[si] : b2f(((const bf16*)src)[si]);
    g_arena[(long)dst_off + i] = f2b(v);
}

// crops NCHW -> arena NHWC3  (out[(n*HW+pix)*3+c])
__global__ void convert_crop_kern(const void* __restrict__ src, int dst_off, int HW, int n)
{
    int i = blockIdx.x * blockDim.x + threadIdx.x;
    if (i >= n) return;
    int c = i % 3;
    int t = i / 3;
    int pix = t % HW;
    int nn = t / HW;
    long si = ((long)(nn * 3 + c)) * HW + pix;
    float v = g_isf32 ? ((const float*)src)[si] : b2f(((const bf16*)src)[si]);
    g_arena[(long)dst_off + i] = f2b(v);
}

struct CvtEnt { const void* src; int dst_off; int n; };
struct CvtTab { CvtEnt e[50]; };
__global__ void convert_many_kern(CvtTab tab)
{
    CvtEnt ent = tab.e[blockIdx.y];
    int i = blockIdx.x * blockDim.x + threadIdx.x;
    if (i >= ent.n) return;
    float v = g_isf32 ? ((const float*)ent.src)[i] : b2f(((const bf16*)ent.src)[i]);
    g_arena[(long)ent.dst_off + i] = f2b(v);
}

__device__ __forceinline__ void stout(void* base, long idx, float v, int f32)
{
    if (f32) ((float*)base)[idx] = v;
    else     ((bf16*)base)[idx] = f2b(v);
}

// ---------------------------------------------------------------------------
// Weight repack for MFMA convs: w[o][c][tap] (torch OIHW) -> wr[o][tap][c].
// ---------------------------------------------------------------------------
__global__ void repack_w_kern(int w_off, int rw_off, int CO, int CIN, int CPAD,
                              int KHW, int total)
{
    int i = blockIdx.x * blockDim.x + threadIdx.x;
    if (i >= total) return;
    int c = i % CPAD;
    int t = i / CPAD;
    int g = t % KHW;
    int o = t / KHW;
    u16 v = 0;
    if (o < CO && c < CIN)
        v = ((const u16*)g_arena)[w_off + ((long)(o * CIN + c)) * KHW + g];
    ((u16*)g_arena)[(long)rw_off + i] = v;
}

// ---------------------------------------------------------------------------
// Tap-pair repack for CIN=3 conv1 layers (9 taps, 3x3):
// wr[o][gp*16 + half*8 + c] = w[o][c][2*gp+half]  (c<3, tap<9; else 0).
// K-group gp: half=0 lanes carry tap 2gp, half=1 lanes carry tap 2gp+1.
// gp=4: tap 8 on half=0; half=1 weights zero.
// ---------------------------------------------------------------------------
__global__ void repack_w3p_kern(int w_off, int rw_off, int CO, int total)
{
    int i = blockIdx.x * blockDim.x + threadIdx.x;
    if (i >= total) return;
    int k = i & 15, t = i >> 4;
    int gp = t % 5, o = t / 5;
    int half = k >> 3, c = k & 7;
    int tap = 2 * gp + half;
    u16 v = 0;
    if (c < 3 && tap < 9 && o < CO)
        v = ((const u16*)g_arena)[w_off + (long)(o * 3 + c) * 9 + tap];
    ((u16*)g_arena)[(long)rw_off + i] = v;
}

// ---------------------------------------------------------------------------
// Crop-net conv1 (CIN=3) via MFMA 32x32x16 bf16, NHWC3 in -> NHWC out.
// v2: tap-pair K packing (5 groups, both halves read real data; 10 MFMA/wave).
// ---------------------------------------------------------------------------
template<int H,int W,int OH,int OW,int CO>
__launch_bounds__(256)
__global__ void conv1_mfma_kern(int in_off, int rw_off, int b_off, int a_off, int out_off)
{
    constexpr int PST = 8;
    constexpr int CO2 = CO + 2;
    __shared__ __align__(16) u16 patchT[10 * W * PST];
    __shared__ __align__(16) u16 out_s[8 * 32 * CO2];

    int n = blockIdx.x, by = blockIdx.y, tx = blockIdx.z;
    int gy0 = by * 8, gx0 = tx * 32;
    const u16* ga = (const u16*)g_arena;

    for (int i = threadIdx.x; i < 10 * W; i += 256)
        *(s16x8*)&patchT[i * PST] = (s16x8){};
    __syncthreads();
    for (int i = threadIdx.x; i < 10 * W * 3; i += 256) {
        int py = i / (W * 3), r = i - py * (W * 3);
        if (gy0 + py < H)
            patchT[(py * W + r / 3) * PST + r % 3] =
                ga[in_off + ((long)(n * H + gy0 + py) * W) * 3 + r];
    }
    __syncthreads();

    int lane = threadIdx.x & 63, w = threadIdx.x >> 6;
    int half = lane >> 5, m = lane & 31;
    int c0 = half * 8;

    s16x8 bfrag[5];
    {
        const u16* wbp = ga + rw_off + m * 80 + c0;
        #pragma unroll
        for (int gp = 0; gp < 5; ++gp)
            bfrag[gp] = *(const s16x8*)(wbp + gp * 16);
    }
    float bb = (m < CO) ? us2f(ga[b_off + m]) : 0.f;
    float aa = (m < CO) ? us2f(ga[a_off + m]) : 0.f;

    // tapA = 2gp (half=0), tapB = min(2gp+1, 8) (half=1; gp=4 weights are 0)
    const int kyA[5] = {0, 0, 1, 2, 2}, kxA[5] = {0, 2, 1, 0, 2};
    const int kyB[5] = {0, 1, 1, 2, 2}, kxB[5] = {1, 0, 2, 1, 2};

    f32x16 acc0 = {}, acc1 = {};
    #pragma unroll
    for (int gp = 0; gp < 5; ++gp) {
        int cxA = gx0 + m + kxA[gp]; if (cxA > W - 1) cxA = W - 1;
        int cxB = gx0 + m + kxB[gp]; if (cxB > W - 1) cxB = W - 1;
        int E = half ? (kyB[gp] * W + cxB) : (kyA[gp] * W + cxA);
        s16x8 a0 = *(const s16x8*)&patchT[((2 * w + 0) * W + E) * PST];
        s16x8 a1 = *(const s16x8*)&patchT[((2 * w + 1) * W + E) * PST];
        acc0 = __builtin_amdgcn_mfma_f32_32x32x16_bf16(a0, bfrag[gp], acc0, 0, 0, 0);
        acc1 = __builtin_amdgcn_mfma_f32_32x32x16_bf16(a1, bfrag[gp], acc1, 0, 0, 0);
    }

    if (m < CO) {
        #pragma unroll
        for (int s = 0; s < 2; ++s) {
            const f32x16& A = s ? acc1 : acc0;
            int r = 2 * w + s;
            #pragma unroll
            for (int reg = 0; reg < 16; ++reg) {
                int x = (reg & 3) + 8 * (reg >> 2) + 4 * half;
                float v = A[reg] + bb;
                v = v > 0.f ? v : v * aa;
                u16 bits; bf16 t = f2b(v); __builtin_memcpy(&bits, &t, 2);
                out_s[(r * 32 + x) * CO2 + m] = bits;
            }
        }
    }
    __syncthreads();

    int nrowv = OH - gy0; if (nrowv > 8) nrowv = 8;
    int ncolv = OW - gx0; if (ncolv > 32) ncolv = 32;
    int cw = ncolv * (CO / 2);
    int totw = nrowv * cw;
    const u32* osrc = (const u32*)out_s;
    for (int i = threadIdx.x; i < totw; i += 256) {
        int r = i / cw, rem = i - r * cw;
        int x = rem / (CO / 2), op = rem - x * (CO / 2);
        u32 v = osrc[(r * 32 + x) * (CO2 / 2) + op];
        *(u32*)&g_arena[(long)out_off +
            (((long)(n * OH + gy0 + r)) * OW + gx0 + x) * CO + 2 * op] = v;
    }
}

// ---------------------------------------------------------------------------
// MFMA conv for channel-rich crop-net layers (CIN >= 16).
// ---------------------------------------------------------------------------
template<int CIN,int CPAD,int KH,int KW,int H,int W,int OH,int OW,int CO,int NT>
__launch_bounds__(256, 2)
__global__ void conv_mfma_kern(int in_off, int rw_off, int b_off, int a_off, int out_off)
{
    constexpr int NPX = OH * OW;
    constexpr int MT = (NPX + 31) / 32;
    constexpr int PST = CPAD + 8;
    constexpr int NCH = CPAD / 16;
    constexpr int KHW = KH * KW;
    constexpr int NG = KHW * NCH;
    __shared__ __align__(16) u16 patchT[H * W * PST];

    int n = blockIdx.x;
    const u16* ga = (const u16*)g_arena;
    const u16* in = ga + in_off + (long)n * (H * W * CIN);

    if constexpr (CIN == CPAD) {
        constexpr int NV = H * W * (CPAD / 8);
        for (int i = threadIdx.x; i < NV; i += 256) {
            int pix = i / (CPAD / 8), j = i % (CPAD / 8);
            *(s16x8*)&patchT[pix * PST + j * 8] = *(const s16x8*)&in[pix * CPAD + j * 8];
        }
    } else {
        constexpr int TOT = H * W * CPAD;
        for (int i = threadIdx.x; i < TOT; i += 256) {
            int pix = i / CPAD, c = i % CPAD;
            patchT[pix * PST + c] = (c < CIN) ? in[pix * CIN + c] : (u16)0;
        }
    }
    __syncthreads();

    int m = threadIdx.x & 31, half = (threadIdx.x >> 5) & 1, wave = threadIdx.x >> 6;
    int c0 = half * 8;
    int nt = wave % NT;
    int o = nt * 32 + m;
    bool ovld = o < CO;
    float bb = ovld ? us2f(ga[b_off + o]) : 0.f;
    float aa = ovld ? us2f(ga[a_off + o]) : 0.f;

    s16x8 bfrag[NG];
    const u16* wb = ga + rw_off + (long)(nt * 32 + m) * (KHW * CPAD) + c0;
    #pragma unroll
    for (int g = 0; g < NG; ++g)
        bfrag[g] = *(const s16x8*)(wb + g * 16);

    for (int mt = wave / NT; mt < MT; mt += 4 / NT) {
        int p = mt * 32 + m;
        int pc = p < NPX ? p : NPX - 1;
        int pp = (pc / OW) * W + (pc % OW);
        f32x16 acc = {};
        #pragma unroll
        for (int t = 0; t < KHW; ++t) {
            int rb = (pp + (t / KW) * W + (t % KW)) * PST + c0;
            #pragma unroll
            for (int ch = 0; ch < NCH; ++ch) {
                s16x8 a = *(const s16x8*)&patchT[rb + ch * 16];
                acc = __builtin_amdgcn_mfma_f32_32x32x16_bf16(a, bfrag[t * NCH + ch], acc, 0, 0, 0);
            }
        }
        if (ovld) {
            bf16* op = g_arena + (long)out_off + (long)n * (NPX * CO) + o;
            #pragma unroll
            for (int reg = 0; reg < 16; ++reg) {
                int mrow = (reg & 3) + 8 * (reg >> 2) + 4 * half;
                int pr = mt * 32 + mrow;
                if (pr < NPX) {
                    float v = acc[reg] + bb;
                    v = v > 0.f ? v : v * aa;
                    op[(long)pr * CO] = f2b(v);
                }
            }
        }
    }
}

// ---------------------------------------------------------------------------
// PNet conv1 (3->10) + PReLU + fused maxpool 2x2 s2 via MFMA 32x32x16 bf16.
// v5: tap-pair K packing — both halves read real LDS (no data-select),
// 20 MFMA/wave (was 36); PST=8, conflict-free A-reads.
// ---------------------------------------------------------------------------
__launch_bounds__(256)
__global__ void pnet_c1m_kern(int b_off, int a_off, int out_off)
{
    constexpr int PST = 8;
    __shared__ __align__(16) u16 patchT[612 * PST];   // 9792 B
    __shared__ __align__(16) u16 out_s[8 * 16 * 10];  // 2560 B
    __shared__ float b1s[16], a1s[16];

    int n = blockIdx.x, by = blockIdx.y, tx = blockIdx.z;
    int gy0 = by * 16, gx0 = tx * 32;
    const u16* ga = (const u16*)g_arena;

    for (int i = threadIdx.x; i < 612; i += 256)
        *(s16x8*)&patchT[i * PST] = (s16x8){};
    if (threadIdx.x < 16) {
        b1s[threadIdx.x] = (threadIdx.x < 10) ? us2f(ga[b_off + threadIdx.x]) : 0.f;
        a1s[threadIdx.x] = (threadIdx.x < 10) ? us2f(ga[a_off + threadIdx.x]) : 0.f;
    }
    __syncthreads();

    for (int i = threadIdx.x; i < 18 * 128; i += 256) {
        int py = i >> 7, r = i & 127;
        if (r < 102) {
            int pxx = r / 3, c = r - pxx * 3;
            int iy = gy0 + py, ix = gx0 + pxx;
            if (iy < 720 && ix < 720)
                patchT[(py * 34 + pxx) * PST + c] =
                    ga[OFF_IMGS + (((long)n * 720 + iy) * 720 + ix) * 3 + c];
        }
    }
    __syncthreads();

    int lane = threadIdx.x & 63, w = threadIdx.x >> 6;
    int half = lane >> 5, m = lane & 31;
    int c0 = half * 8;

    s16x8 bfrag[5];
    {
        const u16* wbp = ga + RW_PC1 + m * 80 + c0;
        #pragma unroll
        for (int gp = 0; gp < 5; ++gp)
            bfrag[gp] = *(const s16x8*)(wbp + gp * 16);
    }

    // D = ky*34 + kx for tapA=2gp (half=0) / tapB=min(2gp+1,8) (half=1)
    const int DA[5] = {0, 2, 35, 68, 70};
    const int DB[5] = {1, 34, 36, 69, 70};

    f32x16 acc[4] = {};
    #pragma unroll
    for (int gp = 0; gp < 5; ++gp) {
        int D = half ? DB[gp] : DA[gp];
        #pragma unroll
        for (int rj = 0; rj < 4; ++rj) {
            s16x8 a = *(const s16x8*)&patchT[((4 * w + rj) * 34 + m + D) * PST];
            acc[rj] = __builtin_amdgcn_mfma_f32_32x32x16_bf16(a, bfrag[gp], acc[rj], 0, 0, 0);
        }
    }

    if (m < 10) {
        float b = b1s[m], al = a1s[m];
        #pragma unroll
        for (int s = 0; s < 2; ++s) {
            int lr = 2 * w + s;
            #pragma unroll
            for (int u = 0; u < 8; ++u) {
                int pxo = (u & 1) + 4 * (u >> 1) + 2 * half;
                float v0 = acc[2 * s][2 * u] + b;         v0 = v0 > 0.f ? v0 : v0 * al;
                float v1 = acc[2 * s][2 * u + 1] + b;     v1 = v1 > 0.f ? v1 : v1 * al;
                float v2 = acc[2 * s + 1][2 * u] + b;     v2 = v2 > 0.f ? v2 : v2 * al;
                float v3 = acc[2 * s + 1][2 * u + 1] + b; v3 = v3 > 0.f ? v3 : v3 * al;
                float mx = fmaxf(fmaxf(v0, v1), fmaxf(v2, v3));
                u16 bits; bf16 t = f2b(mx); __builtin_memcpy(&bits, &t, 2);
                out_s[(lr * 16 + pxo) * 10 + m] = bits;
            }
        }
    }
    __syncthreads();

    int nrowv = 359 - by * 8; if (nrowv > 8) nrowv = 8;
    int ncolv = 359 - tx * 16; if (ncolv > 16) ncolv = 16;
    int cw = ncolv * 5;
    int totw = nrowv * cw;
    for (int i = threadIdx.x; i < totw; i += 256) {
        int j = i / cw, rem = i - j * cw;
        u32 v = ((const u32*)out_s)[j * 80 + rem];
        *(u32*)&g_arena[(long)out_off +
            (((long)n * 359 + by * 8 + j) * 359 + tx * 16) * 10 + rem * 2] = v;
    }
}

// ---------------------------------------------------------------------------
// PNet conv2 (10->16) via MFMA 32x32x16 bf16.  NHWC in (10ch), NHWC out (16ch).
// ---------------------------------------------------------------------------
__launch_bounds__(256)
__global__ void pnet_c2m_kern(int in_off, int b_off, int a_off, int out_off)
{
    constexpr int PST = 24;
    __shared__ __align__(16) u16 patchT[340 * PST];   // 16320 B
    __shared__ float b2s[16], a2s[16];

    int n = blockIdx.x, by = blockIdx.y, tx = blockIdx.z;
    int gy0 = by * 8, gx0 = tx * 32;
    const u16* ga = (const u16*)g_arena;

    for (int i = threadIdx.x; i < 5440; i += 256) {
        int pix = i >> 4, c = i & 15;
        int py = pix / 34, pxx = pix % 34;
        int iy = gy0 + py, ix = gx0 + pxx;
        u16 v = 0;
        if (c < 10 && iy < 359 && ix < 359)
            v = ga[in_off + ((long)(n * 359 + iy) * 359 + ix) * 10 + c];
        patchT[pix * PST + c] = v;
    }
    if (threadIdx.x < 16) {
        b2s[threadIdx.x] = us2f(ga[b_off + threadIdx.x]);
        a2s[threadIdx.x] = us2f(ga[a_off + threadIdx.x]);
    }
    __syncthreads();

    int lane = threadIdx.x & 63, w = threadIdx.x >> 6;
    int half = lane >> 5, m = lane & 31;
    int c0 = half * 8;

    s16x8 bfrag[9];
    {
        const u16* wbp = ga + RW_PC2 + m * 144 + c0;
        #pragma unroll
        for (int g = 0; g < 9; ++g)
            bfrag[g] = *(const s16x8*)(wbp + g * 16);
    }

    f32x16 acc0 = {}, acc1 = {};
    #pragma unroll
    for (int g = 0; g < 9; ++g) {
        int ky = g / 3, kx = g % 3;
        s16x8 a0 = *(const s16x8*)&patchT[((2 * w + 0 + ky) * 34 + m + kx) * PST + c0];
        s16x8 a1 = *(const s16x8*)&patchT[((2 * w + 1 + ky) * 34 + m + kx) * PST + c0];
        acc0 = __builtin_amdgcn_mfma_f32_32x32x16_bf16(a0, bfrag[g], acc0, 0, 0, 0);
        acc1 = __builtin_amdgcn_mfma_f32_32x32x16_bf16(a1, bfrag[g], acc1, 0, 0, 0);
    }

    if (m < 16) {
        float b = b2s[m], al = a2s[m];
        #pragma unroll
        for (int reg = 0; reg < 16; ++reg) {
            int mrow = (reg & 3) + 8 * (reg >> 2) + 4 * half;
            int gy = gy0 + 2 * w, gx = gx0 + mrow;
            if (gy < 357 && gx < 357) {
                float v = acc0[reg] + b; v = v > 0.f ? v : v * al;
                g_arena[(long)out_off + (((long)(n * 357 + gy)) * 357 + gx) * 16 + m] = f2b(v);
            }
            if (gy + 1 < 357 && gx < 357) {
                float v = acc1[reg] + b; v = v > 0.f ? v : v * al;
                g_arena[(long)out_off + (((long)(n * 357 + gy + 1)) * 357 + gx) * 16 + m] = f2b(v);
            }
        }
    }
}

// ---------------------------------------------------------------------------
// PNet conv3 (16->32) + PReLU + heads, conv via MFMA 32x32x16 bf16.
// ---------------------------------------------------------------------------
__launch_bounds__(256)
__global__ void pnet_c3h_kern(int in_off, int b3o, int a3o,
                              int w41o, int b41o, int w42o, int b42o, void* dout)
{
    constexpr int PST = 24;
    __shared__ __align__(16) u16 patchT[340 * PST];   // 16320 B
    __shared__ float c3s[256 * 33];                   // 33792 B
    __shared__ float b3f[32], a3f[32], w41f[64], w42f[128], b41f[2], b42f[4];

    int n = blockIdx.x, by = blockIdx.y, tx = blockIdx.z;
    int gy0 = by * 8, gx0 = tx * 32;
    const u16* ga = (const u16*)g_arena;

    for (int i = threadIdx.x; i < 680; i += 256) {
        int pix = i >> 1, h = i & 1;
        int py = pix / 34, pxx = pix % 34;
        int iy = gy0 + py, ix = gx0 + pxx;
        s16x8 v = {};
        if (iy < 357 && ix < 357)
            v = *(const s16x8*)&ga[in_off + (((long)(n * 357 + iy)) * 357 + ix) * 16 + h * 8];
        *(s16x8*)&patchT[pix * PST + h * 8] = v;
    }
    for (int i = threadIdx.x; i < 32; i += 256) { b3f[i] = us2f(ga[b3o + i]); a3f[i] = us2f(ga[a3o + i]); }
    for (int i = threadIdx.x; i < 64; i += 256) w41f[i] = us2f(ga[w41o + i]);
    for (int i = threadIdx.x; i < 128; i += 256) w42f[i] = us2f(ga[w42o + i]);
    if (threadIdx.x < 2) b41f[threadIdx.x] = us2f(ga[b41o + threadIdx.x]);
    if (threadIdx.x < 4) b42f[threadIdx.x] = us2f(ga[b42o + threadIdx.x]);
    __syncthreads();

    int lane = threadIdx.x & 63, w = threadIdx.x >> 6;
    int half = lane >> 5, m = lane & 31;
    int c0 = half * 8;

    s16x8 bfrag[9];
    {
        const u16* wbp = ga + RW_PC3 + m * 144 + c0;
        #pragma unroll
        for (int g = 0; g < 9; ++g)
            bfrag[g] = *(const s16x8*)(wbp + g * 16);
    }

    f32x16 acc0 = {}, acc1 = {};
    #pragma unroll
    for (int g = 0; g < 9; ++g) {
        int ky = g / 3, kx = g % 3;
        s16x8 a0 = *(const s16x8*)&patchT[((2 * w + 0 + ky) * 34 + m + kx) * PST + c0];
        s16x8 a1 = *(const s16x8*)&patchT[((2 * w + 1 + ky) * 34 + m + kx) * PST + c0];
        acc0 = __builtin_amdgcn_mfma_f32_32x32x16_bf16(a0, bfrag[g], acc0, 0, 0, 0);
        acc1 = __builtin_amdgcn_mfma_f32_32x32x16_bf16(a1, bfrag[g], acc1, 0, 0, 0);
    }

    {
        float b = b3f[m], al = a3f[m];
        #pragma unroll
        for (int reg = 0; reg < 16; ++reg) {
            int mrow = (reg & 3) + 8 * (reg >> 2) + 4 * half;
            float v0 = acc0[reg] + b; v0 = v0 > 0.f ? v0 : v0 * al;
            c3s[(w * 64 + mrow) * 33 + m] = v0;
            float v1 = acc1[reg] + b; v1 = v1 > 0.f ? v1 : v1 * al;
            c3s[(w * 64 + 32 + mrow) * 33 + m] = v1;
        }
    }
    __syncthreads();

    int p = threadIdx.x;
    int gy = gy0 + (p >> 5), gx = gx0 + (p & 31);
    if (gy < 355 && gx < 355) {
        int f32 = g_isf32;
        float l0 = b41f[0], l1 = b41f[1];
        float r0 = b42f[0], r1 = b42f[1], r2 = b42f[2], r3 = b42f[3];
        #pragma unroll
        for (int o = 0; o < 32; ++o) {
            float v = c3s[p * 33 + o];
            l0 += v * w41f[o];
            l1 += v * w41f[32 + o];
            r0 += v * w42f[o];
            r1 += v * w42f[32 + o];
            r2 += v * w42f[64 + o];
            r3 += v * w42f[96 + o];
        }
        float mx = fmaxf(l0, l1);
        float e0 = __expf(l0 - mx), e1 = __expf(l1 - mx);
        float inv = 1.f / (e0 + e1);
        const long HW = 355L * 355L;
        long pix = (long)gy * 355 + gx;
        stout(dout, 4032800 + ((long)n * 2 + 0) * HW + pix, e0 * inv, f32);
        stout(dout, 4032800 + ((long)n * 2 + 1) * HW + pix, e1 * inv, f32);
        stout(dout, ((long)n * 4 + 0) * HW + pix, r0, f32);
        stout(dout, ((long)n * 4 + 1) * HW + pix, r1, f32);
        stout(dout, ((long)n * 4 + 2) * HW + pix, r2, f32);
        stout(dout, ((long)n * 4 + 3) * HW + pix, r3, f32);
    }
}

// ---------------------------------------------------------------------------
// MaxPool2d ceil_mode, NHWC -> NHWC (fully coalesced both sides).
// ---------------------------------------------------------------------------
__global__ void maxpool_nhwc_kern(int in_off, int out_off, int C, int H, int W,
                                  int OH, int OW, int k, int s, int total)
{
    int tid = blockIdx.x * blockDim.x + threadIdx.x;
    if (tid >= total) return;
    int c = tid % C; int t = tid / C;
    int ox = t % OW; t /= OW;
    int oy = t % OH; int n = t / OH;
    const u16* ip = (const u16*)g_arena + in_off + (long)n * H * W * C + c;
    int sy = oy * s, sx = ox * s;
    float m = -1e30f;
    for (int ky = 0; ky < k; ++ky) {
        int iy = sy + ky;
        if (iy >= H) break;
        for (int kx = 0; kx < k; ++kx) {
            int ix = sx + kx;
            if (ix >= W) break;
            m = fmaxf(m, us2f(ip[(iy * W + ix) * C]));
        }
    }
    g_arena[(long)out_off + tid] = f2b(m);
}

// ---------------------------------------------------------------------------
// Flatten from NHWC: torch permute(0,3,2,1).view == h<->w swap on NHWC.
// ---------------------------------------------------------------------------
__global__ void flatten_hw_kern(int in_off, int out_off, int C, int H, int W, int total)
{
    int tid = blockIdx.x * blockDim.x + threadIdx.x;
    if (tid >= total) return;
    int CHW = C * H * W;
    int n = tid / CHW;
    int k = tid % CHW;
    int w = k / (H * C);
    int r = k % (H * C);
    int h = r / C;
    int c = r % C;
    g_arena[(long)out_off + tid] =
        g_arena[(long)in_off + ((long)n * H * W + h * W + w) * C + c];
}

// ---------------------------------------------------------------------------
// Dense + bias + PReLU as tiled LDS GEMM (32x32 tile, 2x2 micro-tile).
// ---------------------------------------------------------------------------
__launch_bounds__(256)
__global__ void dense_tile_kern(int in_off, int w_off, int b_off, int a_off, int out_off,
                                int K, int J)
{
    __shared__ u16 in_s[32 * 66];
    __shared__ u16 w_s[32 * 66];
    int n0 = blockIdx.x * 32, j0 = blockIdx.y * 32;
    const u16* ga = (const u16*)g_arena;
    const u16* fin = ga + in_off;
    const u16* wts = ga + w_off;
    int sy = threadIdx.x >> 4, sx = threadIdx.x & 15;

    float acc00 = 0.f, acc01 = 0.f, acc10 = 0.f, acc11 = 0.f;

    for (int kc = 0; kc < K; kc += 64) {
        #pragma unroll
        for (int it = 0; it < 4; ++it) {
            int i = threadIdx.x + it * 256;
            int row = i >> 5, c2 = i & 31;
            u32 v = *(const u32*)(fin + (long)(n0 + row) * K + kc + c2 * 2);
            *(u32*)&in_s[row * 66 + c2 * 2] = v;
            u32 wv = *(const u32*)(wts + (long)(j0 + row) * K + kc + c2 * 2);
            *(u32*)&w_s[row * 66 + c2 * 2] = wv;
        }
        __syncthreads();
        #pragma unroll
        for (int kk = 0; kk < 64; ++kk) {
            float a0 = us2f(in_s[(2 * sy) * 66 + kk]);
            float a1 = us2f(in_s[(2 * sy + 1) * 66 + kk]);
            float b0 = us2f(w_s[(2 * sx) * 66 + kk]);
            float b1 = us2f(w_s[(2 * sx + 1) * 66 + kk]);
            acc00 += a0 * b0; acc01 += a0 * b1;
            acc10 += a1 * b0; acc11 += a1 * b1;
        }
        __syncthreads();
    }

    float accs[2][2] = {{acc00, acc01}, {acc10, acc11}};
    #pragma unroll
    for (int jj = 0; jj < 2; ++jj) {
        int j = j0 + 2 * sx + jj;
        float b = us2f(ga[b_off + j]);
        float al = us2f(ga[a_off + j]);
        #pragma unroll
        for (int ss = 0; ss < 2; ++ss) {
            int n = n0 + 2 * sy + ss;
            float v = accs[ss][jj] + b;
            v = v > 0.f ? v : v * al;
            g_arena[(long)out_off + (long)n * J + j] = f2b(v);
        }
    }
}

// ---------------------------------------------------------------------------
// Heads, wave-per-sample: 64 lanes partition K; butterfly shuffle reduction.
// ---------------------------------------------------------------------------
template<int K, int J1, int J2>
__launch_bounds__(256)
__global__ void heads_wave_kern(int fc_off, int wSo, int bSo, int w1o, int b1o,
                                int w2o, int b2o, void* dout,
                                long outS_off, long out1_off, long out2_off, int N)
{
    constexpr int KPL = K / 64;
    constexpr int NACC = 2 + J1 + J2;
    int wave = (blockIdx.x * blockDim.x + threadIdx.x) >> 6;
    int lane = threadIdx.x & 63;
    if (wave >= N) return;
    const u16* ga = (const u16*)g_arena;
    const u16* f  = ga + fc_off + (long)wave * K;
    const u16* wS = ga + wSo;
    const u16* w1 = ga + w1o;
    const u16* w2 = ga + w2o;

    float acc[NACC];
    #pragma unroll
    for (int j = 0; j < NACC; ++j) acc[j] = 0.f;

    #pragma unroll
    for (int kk = 0; kk < KPL; ++kk) {
        int k = lane + kk * 64;
        float fv = us2f(f[k]);
        acc[0] += fv * us2f(wS[k]);
        acc[1] += fv * us2f(wS[K + k]);
        #pragma unroll
        for (int j = 0; j < J1; ++j)
            acc[2 + j] += fv * us2f(w1[j * K + k]);
        #pragma unroll
        for (int j = 0; j < J2; ++j)
            acc[2 + J1 + j] += fv * us2f(w2[j * K + k]);
    }
    #pragma unroll
    for (int j = 0; j < NACC; ++j)
        #pragma unroll
        for (int off = 32; off > 0; off >>= 1)
            acc[j] += __shfl_xor(acc[j], off, 64);

    if (lane == 0) {
        int f32 = g_isf32;
        float l0 = acc[0] + us2f(ga[bSo + 0]);
        float l1 = acc[1] + us2f(ga[bSo + 1]);
        float m = fmaxf(l0, l1);
        float e0 = __expf(l0 - m), e1 = __expf(l1 - m);
        float inv = 1.f / (e0 + e1);
        stout(dout, outS_off + (long)wave * 2 + 0, e0 * inv, f32);
        stout(dout, outS_off + (long)wave * 2 + 1, e1 * inv, f32);
        #pragma unroll
        for (int j = 0; j < J1; ++j)
            stout(dout, out1_off + (long)wave * J1 + j, acc[2 + j] + us2f(ga[b1o + j]), f32);
        #pragma unroll
        for (int j = 0; j < J2; ++j)
            stout(dout, out2_off + (long)wave * J2 + j, acc[2 + J1 + j] + us2f(ga[b2o + j]), f32);
    }
}

static inline dim3 g1(int total) { return dim3((unsigned)((total + 255) / 256)); }

extern "C" void kernel_launch(void* const* d_in, const int* in_sizes, int n_in,
                              void* d_out, int out_size, void* d_ws, size_t ws_size,
                              hipStream_t stream)
{
    int woff[53];
    int acc = OFF_WTS;
    int mx = 0;
    for (int i = 3; i < 53; ++i) { woff[i] = acc; acc += in_sizes[i]; if (in_sizes[i] > mx) mx = in_sizes[i]; }

    detect_kern<<<1, 64, 0, stream>>>(d_in[0]);
    convert_img_kern<<<g1(12441600), 256, 0, stream>>>(d_in[0], OFF_IMGS, 12441600);
    convert_crop_kern<<<g1(3538944), 256, 0, stream>>>(d_in[1], OFF_C24, 576, 3538944);
    convert_crop_kern<<<g1(3538944), 256, 0, stream>>>(d_in[2], OFF_C48, 2304, 3538944);
    CvtTab tab;
    for (int i = 3; i < 53; ++i) tab.e[i - 3] = CvtEnt{ d_in[i], woff[i], in_sizes[i] };
    convert_many_kern<<<dim3((unsigned)((mx + 255) / 256), 50), 256, 0, stream>>>(tab);

    // repack weights for the MFMA convs (after convert_many)
    repack_w3p_kern<<<g1(2560), 256, 0, stream>>>(woff[3], RW_PC1, 10, 2560);
    repack_w_kern<<<g1(4608), 256, 0, stream>>>(woff[6], RW_PC2, 16, 10, 16, 9, 4608);
    repack_w_kern<<<g1(4608), 256, 0, stream>>>(woff[9], RW_PC3, 32, 16, 16, 9, 4608);
    repack_w3p_kern<<<g1(2560), 256, 0, stream>>>(woff[16], RW_RC1, 28, 2560);
    repack_w_kern<<<g1(18432), 256, 0, stream>>>(woff[19], RW_RC2, 48, 28, 32, 9, 18432);
    repack_w_kern<<<g1(12288), 256, 0, stream>>>(woff[22], RW_RC3, 64, 48, 48, 4, 12288);
    repack_w3p_kern<<<g1(2560), 256, 0, stream>>>(woff[32], RW_OC1, 32, 2560);
    repack_w_kern<<<g1(18432), 256, 0, stream>>>(woff[35], RW_OC2, 64, 32, 32, 9, 18432);
    repack_w_kern<<<g1(36864), 256, 0, stream>>>(woff[38], RW_OC3, 64, 64, 64, 9, 36864);
    repack_w_kern<<<g1(32768), 256, 0, stream>>>(woff[41], RW_OC4, 128, 64, 64, 4, 32768);

    // ================= PNet (NHWC end-to-end) =================
    pnet_c1m_kern<<<dim3(8, 45, 23), 256, 0, stream>>>(woff[4], woff[5], OFF_A);
    pnet_c2m_kern<<<dim3(8, 45, 12), 256, 0, stream>>>(OFF_A, woff[7], woff[8], OFF_B);
    pnet_c3h_kern<<<dim3(8, 45, 12), 256, 0, stream>>>(OFF_B,
        woff[10], woff[11], woff[12], woff[13], woff[14], woff[15], d_out);

    // ================= RNet (NHWC end-to-end) =================
    conv1_mfma_kern<24,24,22,22,28><<<dim3(2048, 3, 1), 256, 0, stream>>>(
        OFF_C24, RW_RC1, woff[17], woff[18], OFF_A);
    maxpool_nhwc_kern<<<g1(6938624), 256, 0, stream>>>(OFF_A, OFF_B, 28, 22, 22, 11, 11, 3, 2, 6938624);
    conv_mfma_kern<28,32,3,3,11,11,9,9,48,2><<<dim3(2048), 256, 0, stream>>>(
        OFF_B, RW_RC2, woff[20], woff[21], OFF_A);
    maxpool_nhwc_kern<<<g1(1572864), 256, 0, stream>>>(OFF_A, OFF_B, 48, 9, 9, 4, 4, 3, 2, 1572864);
    conv_mfma_kern<48,48,2,2,4,4,3,3,64,2><<<dim3(2048), 256, 0, stream>>>(
        OFF_B, RW_RC3, woff[23], woff[24], OFF_A);
    flatten_hw_kern<<<g1(1179648), 256, 0, stream>>>(OFF_A, OFF_B, 64, 3, 3, 1179648);
    dense_tile_kern<<<dim3(64, 4), 256, 0, stream>>>(OFF_B, woff[25], woff[26], woff[27], OFF_A,
        576, 128);
    heads_wave_kern<128,4,0><<<dim3(512), 256, 0, stream>>>(OFF_A,
        woff[28], woff[29], woff[30], woff[31], 0, 0,
        d_out, 6057392L, 6049200L, 0L, 2048);

    // ================= ONet (NHWC end-to-end) =================
    conv1_mfma_kern<48,48,46,46,32><<<dim3(512, 6, 2), 256, 0, stream>>>(
        OFF_C48, RW_OC1, woff[33], woff[34], OFF_A);
    maxpool_nhwc_kern<<<g1(8667136), 256, 0, stream>>>(OFF_A, OFF_B, 32, 46, 46, 23, 23, 3, 2, 8667136);
    conv_mfma_kern<32,32,3,3,23,23,21,21,64,2><<<dim3(512), 256, 0, stream>>>(
        OFF_B, RW_OC2, woff[36], woff[37], OFF_A);
    maxpool_nhwc_kern<<<g1(3276800), 256, 0, stream>>>(OFF_A, OFF_B, 64, 21, 21, 10, 10, 3, 2, 3276800);
    conv_mfma_kern<64,64,3,3,10,10,8,8,64,2><<<dim3(512), 256, 0, stream>>>(
        OFF_B, RW_OC3, woff[39], woff[40], OFF_A);
    maxpool_nhwc_kern<<<g1(524288), 256, 0, stream>>>(OFF_A, OFF_B, 64, 8, 8, 4, 4, 2, 2, 524288);
    conv_mfma_kern<64,64,2,2,4,4,3,3,128,4><<<dim3(512), 256, 0, stream>>>(
        OFF_B, RW_OC4, woff[42], woff[43], OFF_A);
    flatten_hw_kern<<<g1(589824), 256, 0, stream>>>(OFF_A, OFF_B, 128, 3, 3, 589824);
    dense_tile_kern<<<dim3(16, 8), 256, 0, stream>>>(OFF_B, woff[44], woff[45], woff[46], OFF_A,
        1152, 256);
    heads_wave_kern<256,4,10><<<dim3(128), 256, 0, stream>>>(OFF_A,
        woff[47], woff[48], woff[49], woff[50], woff[51], woff[52],
        d_out, 6068656L, 6061488L, 6063536L, 512);
}

// Round 11
// 795.129 us; speedup vs baseline: 1.0903x; 1.0533x over previous
//
#include <hip/hip_runtime.h>
#include <hip/hip_bf16.h>

typedef __hip_bfloat16 bf16;
typedef unsigned short u16;
typedef unsigned int u32;

typedef float f32x16 __attribute__((ext_vector_type(16)));
typedef short s16x8 __attribute__((ext_vector_type(8)));

__device__ __forceinline__ float b2f(bf16 v) { return __bfloat162float(v); }
__device__ __forceinline__ bf16  f2b(float v) { return __float2bfloat16(v); }
__device__ __forceinline__ float us2f(u16 u) { return __uint_as_float((u32)u << 16); }
__device__ __forceinline__ float ulo(u32 u)  { return __uint_as_float(u << 16); }
__device__ __forceinline__ float uhi(u32 u)  { return __uint_as_float(u & 0xFFFF0000u); }

// ---------------------------------------------------------------------------
// Static device arena (BSS, ~143 MB).  imgs NHWC3; crops NHWC3.
// ---------------------------------------------------------------------------
#define OFF_IMGS 0
#define OFF_C24  12441600
#define OFF_C48  15980544
#define OFF_WTS  19519488
#define OFF_A    20119488
#define OFF_B    54819488
#define OFF_RW   71319488
// repacked weights
#define RW_RC2   (OFF_RW)            // 64 x  9x32 = 18432
#define RW_RC3   (OFF_RW + 18432)    // 64 x  4x48 = 12288
#define RW_OC2   (OFF_RW + 30720)    // 64 x  9x32 = 18432
#define RW_OC3   (OFF_RW + 49152)    // 64 x  9x64 = 36864
#define RW_OC4   (OFF_RW + 86016)    // 128 x 4x64 = 32768
#define RW_PC1   (OFF_RW + 118784)   // 32 x 5x16 = 2560 (tap-pair packed)
#define RW_PC2   (OFF_RW + 123392)   // 32 x 9x16 = 4608
#define RW_PC3   (OFF_RW + 128000)   // 32 x 9x16 = 4608
#define RW_RC1   (OFF_RW + 132608)   // 32 x 5x16 = 2560 (tap-pair packed)
#define RW_OC1   (OFF_RW + 137216)   // 32 x 5x16 = 2560 (tap-pair packed)
#define ARENA_N  (OFF_RW + 141824L)

__device__ bf16 g_arena[ARENA_N];
__device__ int  g_isf32;

// ---------------------------------------------------------------------------
// Dtype detection (bf16 N(0,1) never has exponent >= 0x8D; fp32 misread does).
// ---------------------------------------------------------------------------
__global__ void detect_kern(const void* imgs)
{
    if (threadIdx.x != 0) return;
    const u16* u = (const u16*)imgs;
    int f32 = 0;
    for (int i = 0; i < 256; ++i) {
        int e = (u[i] >> 7) & 0xFF;
        if (e >= 0x8D) f32 = 1;
    }
    g_isf32 = f32;
}

// imgs NCHW -> arena NHWC3, LDS-staged: block = one image row.
// Coalesced plane-segment reads -> LDS interleave -> contiguous u32 writes.
__global__ void convert_img_kern(const void* __restrict__ src, int dst_off)
{
    __shared__ __align__(4) u16 row_s[2160];
    int n = blockIdx.x, y = blockIdx.y;
    int f32 = g_isf32;
    for (int i = threadIdx.x; i < 2160; i += 256) {
        int c = i / 720, x = i - c * 720;
        long si = ((long)(n * 3 + c) * 720 + y) * 720 + x;
        float v = f32 ? ((const float*)src)[si] : b2f(((const bf16*)src)[si]);
        bf16 t = f2b(v); u16 bits; __builtin_memcpy(&bits, &t, 2);
        row_s[x * 3 + c] = bits;
    }
    __syncthreads();
    u32* dst = (u32*)&g_arena[(long)dst_off + ((long)n * 720 + y) * 2160];
    const u32* srw = (const u32*)row_s;
    for (int i = threadIdx.x; i < 1080; i += 256) dst[i] = srw[i];
}

// crops NCHW -> arena NHWC3  (out[(n*HW+pix)*3+c])
__global__ void convert_crop_kern(const void* __restrict__ src, int dst_off, int HW, int n)
{
    int i = blockIdx.x * blockDim.x + threadIdx.x;
    if (i >= n) return;
    int c = i % 3;
    int t = i / 3;
    int pix = t % HW;
    int nn = t / HW;
    long si = ((long)(nn * 3 + c)) * HW + pix;
    float v = g_isf32 ? ((const float*)src)[si] : b2f(((const bf16*)src)[si]);
    g_arena[(long)dst_off + i] = f2b(v);
}

struct CvtEnt { const void* src; int dst_off; int n; };
struct CvtTab { CvtEnt e[50]; };
__global__ void convert_many_kern(CvtTab tab)
{
    CvtEnt ent = tab.e[blockIdx.y];
    int i = blockIdx.x * blockDim.x + threadIdx.x;
    if (i >= ent.n) return;
    float v = g_isf32 ? ((const float*)ent.src)[i] : b2f(((const bf16*)ent.src)[i]);
    g_arena[(long)ent.dst_off + i] = f2b(v);
}

__device__ __forceinline__ void stout(void* base, long idx, float v, int f32)
{
    if (f32) ((float*)base)[idx] = v;
    else     ((bf16*)base)[idx] = f2b(v);
}

// ---------------------------------------------------------------------------
// Weight repack for MFMA convs: w[o][c][tap] (torch OIHW) -> wr[o][tap][c].
// ---------------------------------------------------------------------------
__global__ void repack_w_kern(int w_off, int rw_off, int CO, int CIN, int CPAD,
                              int KHW, int total)
{
    int i = blockIdx.x * blockDim.x + threadIdx.x;
    if (i >= total) return;
    int c = i % CPAD;
    int t = i / CPAD;
    int g = t % KHW;
    int o = t / KHW;
    u16 v = 0;
    if (o < CO && c < CIN)
        v = ((const u16*)g_arena)[w_off + ((long)(o * CIN + c)) * KHW + g];
    ((u16*)g_arena)[(long)rw_off + i] = v;
}

// ---------------------------------------------------------------------------
// Tap-pair repack for CIN=3 conv1 layers (9 taps, 3x3):
// wr[o][gp*16 + half*8 + c] = w[o][c][2*gp+half]  (c<3, tap<9; else 0).
// ---------------------------------------------------------------------------
__global__ void repack_w3p_kern(int w_off, int rw_off, int CO, int total)
{
    int i = blockIdx.x * blockDim.x + threadIdx.x;
    if (i >= total) return;
    int k = i & 15, t = i >> 4;
    int gp = t % 5, o = t / 5;
    int half = k >> 3, c = k & 7;
    int tap = 2 * gp + half;
    u16 v = 0;
    if (c < 3 && tap < 9 && o < CO)
        v = ((const u16*)g_arena)[w_off + (long)(o * 3 + c) * 9 + tap];
    ((u16*)g_arena)[(long)rw_off + i] = v;
}

// ---------------------------------------------------------------------------
// Crop-net conv1 (CIN=3) via MFMA 32x32x16 bf16, NHWC3 in -> NHWC out.
// v3: tap-pair K packing + per-pixel staging (3 loads + 1 vec store; no
// zero pass, no div-by-3 scatter).
// ---------------------------------------------------------------------------
template<int H,int W,int OH,int OW,int CO>
__launch_bounds__(256)
__global__ void conv1_mfma_kern(int in_off, int rw_off, int b_off, int a_off, int out_off)
{
    constexpr int PST = 8;
    constexpr int CO2 = CO + 2;
    __shared__ __align__(16) u16 patchT[10 * W * PST];
    __shared__ __align__(16) u16 out_s[8 * 32 * CO2];

    int n = blockIdx.x, by = blockIdx.y, tx = blockIdx.z;
    int gy0 = by * 8, gx0 = tx * 32;
    const u16* ga = (const u16*)g_arena;

    // per-pixel staging: upper 5 lanes of the vector store carry the zeros
    for (int i = threadIdx.x; i < 10 * W; i += 256) {
        int py = i / W, pxx = i - py * W;
        int iy = gy0 + py;
        s16x8 v = {};
        if (iy < H) {
            const u16* p = &ga[in_off + (((long)n * H + iy) * W + pxx) * 3];
            v[0] = (short)p[0]; v[1] = (short)p[1]; v[2] = (short)p[2];
        }
        *(s16x8*)&patchT[i * PST] = v;
    }
    __syncthreads();

    int lane = threadIdx.x & 63, w = threadIdx.x >> 6;
    int half = lane >> 5, m = lane & 31;
    int c0 = half * 8;

    s16x8 bfrag[5];
    {
        const u16* wbp = ga + rw_off + m * 80 + c0;
        #pragma unroll
        for (int gp = 0; gp < 5; ++gp)
            bfrag[gp] = *(const s16x8*)(wbp + gp * 16);
    }
    float bb = (m < CO) ? us2f(ga[b_off + m]) : 0.f;
    float aa = (m < CO) ? us2f(ga[a_off + m]) : 0.f;

    // tapA = 2gp (half=0), tapB = 2gp+1 clamped (half=1; gp=4 weights are 0)
    const int kyA[5] = {0, 0, 1, 2, 2}, kxA[5] = {0, 2, 1, 0, 2};
    const int kyB[5] = {0, 1, 1, 2, 2}, kxB[5] = {1, 0, 2, 1, 2};

    f32x16 acc0 = {}, acc1 = {};
    #pragma unroll
    for (int gp = 0; gp < 5; ++gp) {
        int cxA = gx0 + m + kxA[gp]; if (cxA > W - 1) cxA = W - 1;
        int cxB = gx0 + m + kxB[gp]; if (cxB > W - 1) cxB = W - 1;
        int E = half ? (kyB[gp] * W + cxB) : (kyA[gp] * W + cxA);
        s16x8 a0 = *(const s16x8*)&patchT[((2 * w + 0) * W + E) * PST];
        s16x8 a1 = *(const s16x8*)&patchT[((2 * w + 1) * W + E) * PST];
        acc0 = __builtin_amdgcn_mfma_f32_32x32x16_bf16(a0, bfrag[gp], acc0, 0, 0, 0);
        acc1 = __builtin_amdgcn_mfma_f32_32x32x16_bf16(a1, bfrag[gp], acc1, 0, 0, 0);
    }

    if (m < CO) {
        #pragma unroll
        for (int s = 0; s < 2; ++s) {
            const f32x16& A = s ? acc1 : acc0;
            int r = 2 * w + s;
            #pragma unroll
            for (int reg = 0; reg < 16; ++reg) {
                int x = (reg & 3) + 8 * (reg >> 2) + 4 * half;
                float v = A[reg] + bb;
                v = v > 0.f ? v : v * aa;
                u16 bits; bf16 t = f2b(v); __builtin_memcpy(&bits, &t, 2);
                out_s[(r * 32 + x) * CO2 + m] = bits;
            }
        }
    }
    __syncthreads();

    int nrowv = OH - gy0; if (nrowv > 8) nrowv = 8;
    int ncolv = OW - gx0; if (ncolv > 32) ncolv = 32;
    int cw = ncolv * (CO / 2);
    int totw = nrowv * cw;
    const u32* osrc = (const u32*)out_s;
    for (int i = threadIdx.x; i < totw; i += 256) {
        int r = i / cw, rem = i - r * cw;
        int x = rem / (CO / 2), op = rem - x * (CO / 2);
        u32 v = osrc[(r * 32 + x) * (CO2 / 2) + op];
        *(u32*)&g_arena[(long)out_off +
            (((long)(n * OH + gy0 + r)) * OW + gx0 + x) * CO + 2 * op] = v;
    }
}

// ---------------------------------------------------------------------------
// MFMA conv for channel-rich crop-net layers (CIN >= 16).
// ---------------------------------------------------------------------------
template<int CIN,int CPAD,int KH,int KW,int H,int W,int OH,int OW,int CO,int NT>
__launch_bounds__(256, 2)
__global__ void conv_mfma_kern(int in_off, int rw_off, int b_off, int a_off, int out_off)
{
    constexpr int NPX = OH * OW;
    constexpr int MT = (NPX + 31) / 32;
    constexpr int PST = CPAD + 8;
    constexpr int NCH = CPAD / 16;
    constexpr int KHW = KH * KW;
    constexpr int NG = KHW * NCH;
    __shared__ __align__(16) u16 patchT[H * W * PST];

    int n = blockIdx.x;
    const u16* ga = (const u16*)g_arena;
    const u16* in = ga + in_off + (long)n * (H * W * CIN);

    if constexpr (CIN == CPAD) {
        constexpr int NV = H * W * (CPAD / 8);
        for (int i = threadIdx.x; i < NV; i += 256) {
            int pix = i / (CPAD / 8), j = i % (CPAD / 8);
            *(s16x8*)&patchT[pix * PST + j * 8] = *(const s16x8*)&in[pix * CPAD + j * 8];
        }
    } else {
        constexpr int TOT = H * W * CPAD;
        for (int i = threadIdx.x; i < TOT; i += 256) {
            int pix = i / CPAD, c = i % CPAD;
            patchT[pix * PST + c] = (c < CIN) ? in[pix * CIN + c] : (u16)0;
        }
    }
    __syncthreads();

    int m = threadIdx.x & 31, half = (threadIdx.x >> 5) & 1, wave = threadIdx.x >> 6;
    int c0 = half * 8;
    int nt = wave % NT;
    int o = nt * 32 + m;
    bool ovld = o < CO;
    float bb = ovld ? us2f(ga[b_off + o]) : 0.f;
    float aa = ovld ? us2f(ga[a_off + o]) : 0.f;

    s16x8 bfrag[NG];
    const u16* wb = ga + rw_off + (long)(nt * 32 + m) * (KHW * CPAD) + c0;
    #pragma unroll
    for (int g = 0; g < NG; ++g)
        bfrag[g] = *(const s16x8*)(wb + g * 16);

    for (int mt = wave / NT; mt < MT; mt += 4 / NT) {
        int p = mt * 32 + m;
        int pc = p < NPX ? p : NPX - 1;
        int pp = (pc / OW) * W + (pc % OW);
        f32x16 acc = {};
        #pragma unroll
        for (int t = 0; t < KHW; ++t) {
            int rb = (pp + (t / KW) * W + (t % KW)) * PST + c0;
            #pragma unroll
            for (int ch = 0; ch < NCH; ++ch) {
                s16x8 a = *(const s16x8*)&patchT[rb + ch * 16];
                acc = __builtin_amdgcn_mfma_f32_32x32x16_bf16(a, bfrag[t * NCH + ch], acc, 0, 0, 0);
            }
        }
        if (ovld) {
            bf16* op = g_arena + (long)out_off + (long)n * (NPX * CO) + o;
            #pragma unroll
            for (int reg = 0; reg < 16; ++reg) {
                int mrow = (reg & 3) + 8 * (reg >> 2) + 4 * half;
                int pr = mt * 32 + mrow;
                if (pr < NPX) {
                    float v = acc[reg] + bb;
                    v = v > 0.f ? v : v * aa;
                    op[(long)pr * CO] = f2b(v);
                }
            }
        }
    }
}

// ---------------------------------------------------------------------------
// PNet conv1 (3->10) + PReLU + fused maxpool 2x2 s2 via MFMA 32x32x16 bf16.
// v6: per-pixel staging (no zero pass / div-by-3 scatter) + monotone pool
// (PReLU alpha>0 and +bias are monotone: max first, then bias+PReLU once).
// ---------------------------------------------------------------------------
__launch_bounds__(256)
__global__ void pnet_c1m_kern(int b_off, int a_off, int out_off)
{
    constexpr int PST = 8;
    __shared__ __align__(16) u16 patchT[612 * PST];   // 9792 B
    __shared__ __align__(16) u16 out_s[8 * 16 * 10];  // 2560 B
    __shared__ float b1s[16], a1s[16];

    int n = blockIdx.x, by = blockIdx.y, tx = blockIdx.z;
    int gy0 = by * 16, gx0 = tx * 32;
    const u16* ga = (const u16*)g_arena;

    if (threadIdx.x < 16) {
        b1s[threadIdx.x] = (threadIdx.x < 10) ? us2f(ga[b_off + threadIdx.x]) : 0.f;
        a1s[threadIdx.x] = (threadIdx.x < 10) ? us2f(ga[a_off + threadIdx.x]) : 0.f;
    }
    // per-pixel staging: 3 contiguous u16 loads + 1 vector store (zeros c3..7)
    for (int i = threadIdx.x; i < 612; i += 256) {
        int py = i / 34, pxx = i - py * 34;
        int iy = gy0 + py, ix = gx0 + pxx;
        s16x8 v = {};
        if (iy < 720 && ix < 720) {
            const u16* p = &ga[OFF_IMGS + (((long)n * 720 + iy) * 720 + ix) * 3];
            v[0] = (short)p[0]; v[1] = (short)p[1]; v[2] = (short)p[2];
        }
        *(s16x8*)&patchT[i * PST] = v;
    }
    __syncthreads();

    int lane = threadIdx.x & 63, w = threadIdx.x >> 6;
    int half = lane >> 5, m = lane & 31;
    int c0 = half * 8;

    s16x8 bfrag[5];
    {
        const u16* wbp = ga + RW_PC1 + m * 80 + c0;
        #pragma unroll
        for (int gp = 0; gp < 5; ++gp)
            bfrag[gp] = *(const s16x8*)(wbp + gp * 16);
    }

    // D = ky*34 + kx for tapA=2gp (half=0) / tapB (half=1)
    const int DA[5] = {0, 2, 35, 68, 70};
    const int DB[5] = {1, 34, 36, 69, 70};

    f32x16 acc[4] = {};
    #pragma unroll
    for (int gp = 0; gp < 5; ++gp) {
        int D = half ? DB[gp] : DA[gp];
        #pragma unroll
        for (int rj = 0; rj < 4; ++rj) {
            s16x8 a = *(const s16x8*)&patchT[((4 * w + rj) * 34 + m + D) * PST];
            acc[rj] = __builtin_amdgcn_mfma_f32_32x32x16_bf16(a, bfrag[gp], acc[rj], 0, 0, 0);
        }
    }

    // monotone pool: max of 4 raw accs, then bias + PReLU once
    if (m < 10) {
        float b = b1s[m], al = a1s[m];
        #pragma unroll
        for (int s = 0; s < 2; ++s) {
            int lr = 2 * w + s;
            #pragma unroll
            for (int u = 0; u < 8; ++u) {
                int pxo = (u & 1) + 4 * (u >> 1) + 2 * half;
                float mx = fmaxf(fmaxf(acc[2 * s][2 * u], acc[2 * s][2 * u + 1]),
                                 fmaxf(acc[2 * s + 1][2 * u], acc[2 * s + 1][2 * u + 1])) + b;
                mx = mx > 0.f ? mx : mx * al;
                u16 bits; bf16 t = f2b(mx); __builtin_memcpy(&bits, &t, 2);
                out_s[(lr * 16 + pxo) * 10 + m] = bits;
            }
        }
    }
    __syncthreads();

    int nrowv = 359 - by * 8; if (nrowv > 8) nrowv = 8;
    int ncolv = 359 - tx * 16; if (ncolv > 16) ncolv = 16;
    int cw = ncolv * 5;
    int totw = nrowv * cw;
    for (int i = threadIdx.x; i < totw; i += 256) {
        int j = i / cw, rem = i - j * cw;
        u32 v = ((const u32*)out_s)[j * 80 + rem];
        *(u32*)&g_arena[(long)out_off +
            (((long)n * 359 + by * 8 + j) * 359 + tx * 16) * 10 + rem * 2] = v;
    }
}

// ---------------------------------------------------------------------------
// PNet conv2 (10->16) via MFMA 32x32x16 bf16.  NHWC in (10ch), NHWC out (16ch).
// ---------------------------------------------------------------------------
__launch_bounds__(256)
__global__ void pnet_c2m_kern(int in_off, int b_off, int a_off, int out_off)
{
    constexpr int PST = 24;
    __shared__ __align__(16) u16 patchT[340 * PST];   // 16320 B
    __shared__ float b2s[16], a2s[16];

    int n = blockIdx.x, by = blockIdx.y, tx = blockIdx.z;
    int gy0 = by * 8, gx0 = tx * 32;
    const u16* ga = (const u16*)g_arena;

    for (int i = threadIdx.x; i < 5440; i += 256) {
        int pix = i >> 4, c = i & 15;
        int py = pix / 34, pxx = pix % 34;
        int iy = gy0 + py, ix = gx0 + pxx;
        u16 v = 0;
        if (c < 10 && iy < 359 && ix < 359)
            v = ga[in_off + ((long)(n * 359 + iy) * 359 + ix) * 10 + c];
        patchT[pix * PST + c] = v;
    }
    if (threadIdx.x < 16) {
        b2s[threadIdx.x] = us2f(ga[b_off + threadIdx.x]);
        a2s[threadIdx.x] = us2f(ga[a_off + threadIdx.x]);
    }
    __syncthreads();

    int lane = threadIdx.x & 63, w = threadIdx.x >> 6;
    int half = lane >> 5, m = lane & 31;
    int c0 = half * 8;

    s16x8 bfrag[9];
    {
        const u16* wbp = ga + RW_PC2 + m * 144 + c0;
        #pragma unroll
        for (int g = 0; g < 9; ++g)
            bfrag[g] = *(const s16x8*)(wbp + g * 16);
    }

    f32x16 acc0 = {}, acc1 = {};
    #pragma unroll
    for (int g = 0; g < 9; ++g) {
        int ky = g / 3, kx = g % 3;
        s16x8 a0 = *(const s16x8*)&patchT[((2 * w + 0 + ky) * 34 + m + kx) * PST + c0];
        s16x8 a1 = *(const s16x8*)&patchT[((2 * w + 1 + ky) * 34 + m + kx) * PST + c0];
        acc0 = __builtin_amdgcn_mfma_f32_32x32x16_bf16(a0, bfrag[g], acc0, 0, 0, 0);
        acc1 = __builtin_amdgcn_mfma_f32_32x32x16_bf16(a1, bfrag[g], acc1, 0, 0, 0);
    }

    if (m < 16) {
        float b = b2s[m], al = a2s[m];
        #pragma unroll
        for (int reg = 0; reg < 16; ++reg) {
            int mrow = (reg & 3) + 8 * (reg >> 2) + 4 * half;
            int gy = gy0 + 2 * w, gx = gx0 + mrow;
            if (gy < 357 && gx < 357) {
                float v = acc0[reg] + b; v = v > 0.f ? v : v * al;
                g_arena[(long)out_off + (((long)(n * 357 + gy)) * 357 + gx) * 16 + m] = f2b(v);
            }
            if (gy + 1 < 357 && gx < 357) {
                float v = acc1[reg] + b; v = v > 0.f ? v : v * al;
                g_arena[(long)out_off + (((long)(n * 357 + gy + 1)) * 357 + gx) * 16 + m] = f2b(v);
            }
        }
    }
}

// ---------------------------------------------------------------------------
// PNet conv3 (16->32) + PReLU + heads, conv via MFMA 32x32x16 bf16.
// ---------------------------------------------------------------------------
__launch_bounds__(256)
__global__ void pnet_c3h_kern(int in_off, int b3o, int a3o,
                              int w41o, int b41o, int w42o, int b42o, void* dout)
{
    constexpr int PST = 24;
    __shared__ __align__(16) u16 patchT[340 * PST];   // 16320 B
    __shared__ float c3s[256 * 33];                   // 33792 B
    __shared__ float b3f[32], a3f[32], w41f[64], w42f[128], b41f[2], b42f[4];

    int n = blockIdx.x, by = blockIdx.y, tx = blockIdx.z;
    int gy0 = by * 8, gx0 = tx * 32;
    const u16* ga = (const u16*)g_arena;

    for (int i = threadIdx.x; i < 680; i += 256) {
        int pix = i >> 1, h = i & 1;
        int py = pix / 34, pxx = pix % 34;
        int iy = gy0 + py, ix = gx0 + pxx;
        s16x8 v = {};
        if (iy < 357 && ix < 357)
            v = *(const s16x8*)&ga[in_off + (((long)(n * 357 + iy)) * 357 + ix) * 16 + h * 8];
        *(s16x8*)&patchT[pix * PST + h * 8] = v;
    }
    for (int i = threadIdx.x; i < 32; i += 256) { b3f[i] = us2f(ga[b3o + i]); a3f[i] = us2f(ga[a3o + i]); }
    for (int i = threadIdx.x; i < 64; i += 256) w41f[i] = us2f(ga[w41o + i]);
    for (int i = threadIdx.x; i < 128; i += 256) w42f[i] = us2f(ga[w42o + i]);
    if (threadIdx.x < 2) b41f[threadIdx.x] = us2f(ga[b41o + threadIdx.x]);
    if (threadIdx.x < 4) b42f[threadIdx.x] = us2f(ga[b42o + threadIdx.x]);
    __syncthreads();

    int lane = threadIdx.x & 63, w = threadIdx.x >> 6;
    int half = lane >> 5, m = lane & 31;
    int c0 = half * 8;

    s16x8 bfrag[9];
    {
        const u16* wbp = ga + RW_PC3 + m * 144 + c0;
        #pragma unroll
        for (int g = 0; g < 9; ++g)
            bfrag[g] = *(const s16x8*)(wbp + g * 16);
    }

    f32x16 acc0 = {}, acc1 = {};
    #pragma unroll
    for (int g = 0; g < 9; ++g) {
        int ky = g / 3, kx = g % 3;
        s16x8 a0 = *(const s16x8*)&patchT[((2 * w + 0 + ky) * 34 + m + kx) * PST + c0];
        s16x8 a1 = *(const s16x8*)&patchT[((2 * w + 1 + ky) * 34 + m + kx) * PST + c0];
        acc0 = __builtin_amdgcn_mfma_f32_32x32x16_bf16(a0, bfrag[g], acc0, 0, 0, 0);
        acc1 = __builtin_amdgcn_mfma_f32_32x32x16_bf16(a1, bfrag[g], acc1, 0, 0, 0);
    }

    {
        float b = b3f[m], al = a3f[m];
        #pragma unroll
        for (int reg = 0; reg < 16; ++reg) {
            int mrow = (reg & 3) + 8 * (reg >> 2) + 4 * half;
            float v0 = acc0[reg] + b; v0 = v0 > 0.f ? v0 : v0 * al;
            c3s[(w * 64 + mrow) * 33 + m] = v0;
            float v1 = acc1[reg] + b; v1 = v1 > 0.f ? v1 : v1 * al;
            c3s[(w * 64 + 32 + mrow) * 33 + m] = v1;
        }
    }
    __syncthreads();

    int p = threadIdx.x;
    int gy = gy0 + (p >> 5), gx = gx0 + (p & 31);
    if (gy < 355 && gx < 355) {
        int f32 = g_isf32;
        float l0 = b41f[0], l1 = b41f[1];
        float r0 = b42f[0], r1 = b42f[1], r2 = b42f[2], r3 = b42f[3];
        #pragma unroll
        for (int o = 0; o < 32; ++o) {
            float v = c3s[p * 33 + o];
            l0 += v * w41f[o];
            l1 += v * w41f[32 + o];
            r0 += v * w42f[o];
            r1 += v * w42f[32 + o];
            r2 += v * w42f[64 + o];
            r3 += v * w42f[96 + o];
        }
        float mx = fmaxf(l0, l1);
        float e0 = __expf(l0 - mx), e1 = __expf(l1 - mx);
        float inv = 1.f / (e0 + e1);
        const long HW = 355L * 355L;
        long pix = (long)gy * 355 + gx;
        stout(dout, 4032800 + ((long)n * 2 + 0) * HW + pix, e0 * inv, f32);
        stout(dout, 4032800 + ((long)n * 2 + 1) * HW + pix, e1 * inv, f32);
        stout(dout, ((long)n * 4 + 0) * HW + pix, r0, f32);
        stout(dout, ((long)n * 4 + 1) * HW + pix, r1, f32);
        stout(dout, ((long)n * 4 + 2) * HW + pix, r2, f32);
        stout(dout, ((long)n * 4 + 3) * HW + pix, r3, f32);
    }
}

// ---------------------------------------------------------------------------
// MaxPool2d ceil_mode, NHWC -> NHWC (fully coalesced both sides).
// ---------------------------------------------------------------------------
__global__ void maxpool_nhwc_kern(int in_off, int out_off, int C, int H, int W,
                                  int OH, int OW, int k, int s, int total)
{
    int tid = blockIdx.x * blockDim.x + threadIdx.x;
    if (tid >= total) return;
    int c = tid % C; int t = tid / C;
    int ox = t % OW; t /= OW;
    int oy = t % OH; int n = t / OH;
    const u16* ip = (const u16*)g_arena + in_off + (long)n * H * W * C + c;
    int sy = oy * s, sx = ox * s;
    float m = -1e30f;
    for (int ky = 0; ky < k; ++ky) {
        int iy = sy + ky;
        if (iy >= H) break;
        for (int kx = 0; kx < k; ++kx) {
            int ix = sx + kx;
            if (ix >= W) break;
            m = fmaxf(m, us2f(ip[(iy * W + ix) * C]));
        }
    }
    g_arena[(long)out_off + tid] = f2b(m);
}

// ---------------------------------------------------------------------------
// Flatten from NHWC: torch permute(0,3,2,1).view == h<->w swap on NHWC.
// ---------------------------------------------------------------------------
__global__ void flatten_hw_kern(int in_off, int out_off, int C, int H, int W, int total)
{
    int tid = blockIdx.x * blockDim.x + threadIdx.x;
    if (tid >= total) return;
    int CHW = C * H * W;
    int n = tid / CHW;
    int k = tid % CHW;
    int w = k / (H * C);
    int r = k % (H * C);
    int h = r / C;
    int c = r % C;
    g_arena[(long)out_off + tid] =
        g_arena[(long)in_off + ((long)n * H * W + h * W + w) * C + c];
}

// ---------------------------------------------------------------------------
// Dense + bias + PReLU as tiled LDS GEMM (32x32 tile, 2x2 micro-tile).
// ---------------------------------------------------------------------------
__launch_bounds__(256)
__global__ void dense_tile_kern(int in_off, int w_off, int b_off, int a_off, int out_off,
                                int K, int J)
{
    __shared__ u16 in_s[32 * 66];
    __shared__ u16 w_s[32 * 66];
    int n0 = blockIdx.x * 32, j0 = blockIdx.y * 32;
    const u16* ga = (const u16*)g_arena;
    const u16* fin = ga + in_off;
    const u16* wts = ga + w_off;
    int sy = threadIdx.x >> 4, sx = threadIdx.x & 15;

    float acc00 = 0.f, acc01 = 0.f, acc10 = 0.f, acc11 = 0.f;

    for (int kc = 0; kc < K; kc += 64) {
        #pragma unroll
        for (int it = 0; it < 4; ++it) {
            int i = threadIdx.x + it * 256;
            int row = i >> 5, c2 = i & 31;
            u32 v = *(const u32*)(fin + (long)(n0 + row) * K + kc + c2 * 2);
            *(u32*)&in_s[row * 66 + c2 * 2] = v;
            u32 wv = *(const u32*)(wts + (long)(j0 + row) * K + kc + c2 * 2);
            *(u32*)&w_s[row * 66 + c2 * 2] = wv;
        }
        __syncthreads();
        #pragma unroll
        for (int kk = 0; kk < 64; ++kk) {
            float a0 = us2f(in_s[(2 * sy) * 66 + kk]);
            float a1 = us2f(in_s[(2 * sy + 1) * 66 + kk]);
            float b0 = us2f(w_s[(2 * sx) * 66 + kk]);
            float b1 = us2f(w_s[(2 * sx + 1) * 66 + kk]);
            acc00 += a0 * b0; acc01 += a0 * b1;
            acc10 += a1 * b0; acc11 += a1 * b1;
        }
        __syncthreads();
    }

    float accs[2][2] = {{acc00, acc01}, {acc10, acc11}};
    #pragma unroll
    for (int jj = 0; jj < 2; ++jj) {
        int j = j0 + 2 * sx + jj;
        float b = us2f(ga[b_off + j]);
        float al = us2f(ga[a_off + j]);
        #pragma unroll
        for (int ss = 0; ss < 2; ++ss) {
            int n = n0 + 2 * sy + ss;
            float v = accs[ss][jj] + b;
            v = v > 0.f ? v : v * al;
            g_arena[(long)out_off + (long)n * J + j] = f2b(v);
        }
    }
}

// ---------------------------------------------------------------------------
// Heads, wave-per-sample: 64 lanes partition K; butterfly shuffle reduction.
// ---------------------------------------------------------------------------
template<int K, int J1, int J2>
__launch_bounds__(256)
__global__ void heads_wave_kern(int fc_off, int wSo, int bSo, int w1o, int b1o,
                                int w2o, int b2o, void* dout,
                                long outS_off, long out1_off, long out2_off, int N)
{
    constexpr int KPL = K / 64;
    constexpr int NACC = 2 + J1 + J2;
    int wave = (blockIdx.x * blockDim.x + threadIdx.x) >> 6;
    int lane = threadIdx.x & 63;
    if (wave >= N) return;
    const u16* ga = (const u16*)g_arena;
    const u16* f  = ga + fc_off + (long)wave * K;
    const u16* wS = ga + wSo;
    const u16* w1 = ga + w1o;
    const u16* w2 = ga + w2o;

    float acc[NACC];
    #pragma unroll
    for (int j = 0; j < NACC; ++j) acc[j] = 0.f;

    #pragma unroll
    for (int kk = 0; kk < KPL; ++kk) {
        int k = lane + kk * 64;
        float fv = us2f(f[k]);
        acc[0] += fv * us2f(wS[k]);
        acc[1] += fv * us2f(wS[K + k]);
        #pragma unroll
        for (int j = 0; j < J1; ++j)
            acc[2 + j] += fv * us2f(w1[j * K + k]);
        #pragma unroll
        for (int j = 0; j < J2; ++j)
            acc[2 + J1 + j] += fv * us2f(w2[j * K + k]);
    }
    #pragma unroll
    for (int j = 0; j < NACC; ++j)
        #pragma unroll
        for (int off = 32; off > 0; off >>= 1)
            acc[j] += __shfl_xor(acc[j], off, 64);

    if (lane == 0) {
        int f32 = g_isf32;
        float l0 = acc[0] + us2f(ga[bSo + 0]);
        float l1 = acc[1] + us2f(ga[bSo + 1]);
        float m = fmaxf(l0, l1);
        float e0 = __expf(l0 - m), e1 = __expf(l1 - m);
        float inv = 1.f / (e0 + e1);
        stout(dout, outS_off + (long)wave * 2 + 0, e0 * inv, f32);
        stout(dout, outS_off + (long)wave * 2 + 1, e1 * inv, f32);
        #pragma unroll
        for (int j = 0; j < J1; ++j)
            stout(dout, out1_off + (long)wave * J1 + j, acc[2 + j] + us2f(ga[b1o + j]), f32);
        #pragma unroll
        for (int j = 0; j < J2; ++j)
            stout(dout, out2_off + (long)wave * J2 + j, acc[2 + J1 + j] + us2f(ga[b2o + j]), f32);
    }
}

static inline dim3 g1(int total) { return dim3((unsigned)((total + 255) / 256)); }

extern "C" void kernel_launch(void* const* d_in, const int* in_sizes, int n_in,
                              void* d_out, int out_size, void* d_ws, size_t ws_size,
                              hipStream_t stream)
{
    int woff[53];
    int acc = OFF_WTS;
    int mx = 0;
    for (int i = 3; i < 53; ++i) { woff[i] = acc; acc += in_sizes[i]; if (in_sizes[i] > mx) mx = in_sizes[i]; }

    detect_kern<<<1, 64, 0, stream>>>(d_in[0]);
    convert_img_kern<<<dim3(8, 720), 256, 0, stream>>>(d_in[0], OFF_IMGS);
    convert_crop_kern<<<g1(3538944), 256, 0, stream>>>(d_in[1], OFF_C24, 576, 3538944);
    convert_crop_kern<<<g1(3538944), 256, 0, stream>>>(d_in[2], OFF_C48, 2304, 3538944);
    CvtTab tab;
    for (int i = 3; i < 53; ++i) tab.e[i - 3] = CvtEnt{ d_in[i], woff[i], in_sizes[i] };
    convert_many_kern<<<dim3((unsigned)((mx + 255) / 256), 50), 256, 0, stream>>>(tab);

    // repack weights for the MFMA convs (after convert_many)
    repack_w3p_kern<<<g1(2560), 256, 0, stream>>>(woff[3], RW_PC1, 10, 2560);
    repack_w_kern<<<g1(4608), 256, 0, stream>>>(woff[6], RW_PC2, 16, 10, 16, 9, 4608);
    repack_w_kern<<<g1(4608), 256, 0, stream>>>(woff[9], RW_PC3, 32, 16, 16, 9, 4608);
    repack_w3p_kern<<<g1(2560), 256, 0, stream>>>(woff[16], RW_RC1, 28, 2560);
    repack_w_kern<<<g1(18432), 256, 0, stream>>>(woff[19], RW_RC2, 48, 28, 32, 9, 18432);
    repack_w_kern<<<g1(12288), 256, 0, stream>>>(woff[22], RW_RC3, 64, 48, 48, 4, 12288);
    repack_w3p_kern<<<g1(2560), 256, 0, stream>>>(woff[32], RW_OC1, 32, 2560);
    repack_w_kern<<<g1(18432), 256, 0, stream>>>(woff[35], RW_OC2, 64, 32, 32, 9, 18432);
    repack_w_kern<<<g1(36864), 256, 0, stream>>>(woff[38], RW_OC3, 64, 64, 64, 9, 36864);
    repack_w_kern<<<g1(32768), 256, 0, stream>>>(woff[41], RW_OC4, 128, 64, 64, 4, 32768);

    // ================= PNet (NHWC end-to-end) =================
    pnet_c1m_kern<<<dim3(8, 45, 23), 256, 0, stream>>>(woff[4], woff[5], OFF_A);
    pnet_c2m_kern<<<dim3(8, 45, 12), 256, 0, stream>>>(OFF_A, woff[7], woff[8], OFF_B);
    pnet_c3h_kern<<<dim3(8, 45, 12), 256, 0, stream>>>(OFF_B,
        woff[10], woff[11], woff[12], woff[13], woff[14], woff[15], d_out);

    // ================= RNet (NHWC end-to-end) =================
    conv1_mfma_kern<24,24,22,22,28><<<dim3(2048, 3, 1), 256, 0, stream>>>(
        OFF_C24, RW_RC1, woff[17], woff[18], OFF_A);
    maxpool_nhwc_kern<<<g1(6938624), 256, 0, stream>>>(OFF_A, OFF_B, 28, 22, 22, 11, 11, 3, 2, 6938624);
    conv_mfma_kern<28,32,3,3,11,11,9,9,48,2><<<dim3(2048), 256, 0, stream>>>(
        OFF_B, RW_RC2, woff[20], woff[21], OFF_A);
    maxpool_nhwc_kern<<<g1(1572864), 256, 0, stream>>>(OFF_A, OFF_B, 48, 9, 9, 4, 4, 3, 2, 1572864);
    conv_mfma_kern<48,48,2,2,4,4,3,3,64,2><<<dim3(2048), 256, 0, stream>>>(
        OFF_B, RW_RC3, woff[23], woff[24], OFF_A);
    flatten_hw_kern<<<g1(1179648), 256, 0, stream>>>(OFF_A, OFF_B, 64, 3, 3, 1179648);
    dense_tile_kern<<<dim3(64, 4), 256, 0, stream>>>(OFF_B, woff[25], woff[26], woff[27], OFF_A,
        576, 128);
    heads_wave_kern<128,4,0><<<dim3(512), 256, 0, stream>>>(OFF_A,
        woff[28], woff[29], woff[30], woff[31], 0, 0,
        d_out, 6057392L, 6049200L, 0L, 2048);

    // ================= ONet (NHWC end-to-end) =================
    conv1_mfma_kern<48,48,46,46,32><<<dim3(512, 6, 2), 256, 0, stream>>>(
        OFF_C48, RW_OC1, woff[33], woff[34], OFF_A);
    maxpool_nhwc_kern<<<g1(8667136), 256, 0, stream>>>(OFF_A, OFF_B, 32, 46, 46, 23, 23, 3, 2, 8667136);
    conv_mfma_kern<32,32,3,3,23,23,21,21,64,2><<<dim3(512), 256, 0, stream>>>(
        OFF_B, RW_OC2, woff[36], woff[37], OFF_A);
    maxpool_nhwc_kern<<<g1(3276800), 256, 0, stream>>>(OFF_A, OFF_B, 64, 21, 21, 10, 10, 3, 2, 3276800);
    conv_mfma_kern<64,64,3,3,10,10,8,8,64,2><<<dim3(512), 256, 0, stream>>>(
        OFF_B, RW_OC3, woff[39], woff[40], OFF_A);
    maxpool_nhwc_kern<<<g1(524288), 256, 0, stream>>>(OFF_A, OFF_B, 64, 8, 8, 4, 4, 2, 2, 524288);
    conv_mfma_kern<64,64,2,2,4,4,3,3,128,4><<<dim3(512), 256, 0, stream>>>(
        OFF_B, RW_OC4, woff[42], woff[43], OFF_A);
    flatten_hw_kern<<<g1(589824), 256, 0, stream>>>(OFF_A, OFF_B, 128, 3, 3, 589824);
    dense_tile_kern<<<dim3(16, 8), 256, 0, stream>>>(OFF_B, woff[44], woff[45], woff[46], OFF_A,
        1152, 256);
    heads_wave_kern<256,4,10><<<dim3(128), 256, 0, stream>>>(OFF_A,
        woff[47], woff[48], woff[49], woff[50], woff[51], woff[52],
        d_out, 6068656L, 6061488L, 6063536L, 512);
}